// Round 2
// baseline (4189.165 us; speedup 1.0000x reference)
//
#include <hip/hip_runtime.h>
#include <hip/hip_bf16.h>

// RGCN (5 layers, mean aggr per relation, root weight + bias), fp32 baseline v2.
// Change vs v1: workspace usage is ADAPTIVE to ws_size. The per-relation
// transformed-feature buffer H (25.6 MB/relation) is sized to whatever fits:
// RC relations per chunk, looping ceil(12/RC) chunks per layer. RC=12 if
// ws_size >= ~368 MB (same as v1); minimum footprint ~90 MB at RC=1.
// Never writes outside d_ws.

#define N_NODES 50000
#define N_EDGES 800000
#define N_REL   12
#define D_IN    768
#define D_H     128
#define N_GRAPH 64

#define BM 64
#define BN 128
#define BK 32

// ---- GEMM: z < nrel: Hc[z] = A @ W[r0+z];  z >= nrel: Cden = A @ R + bias ----
__global__ __launch_bounds__(256) void gemm_rgcn(
    const float* __restrict__ A,
    const float* __restrict__ W,     // [12,K,128]
    const float* __restrict__ R,     // [K,128]
    const float* __restrict__ bias,  // [128]
    float* __restrict__ Hc,          // [nrel,M,128] chunk buffer
    float* __restrict__ Cden,        // [M,128]
    int M, int K, int r0, int nrel)
{
  const int z = blockIdx.z;
  const bool is_root = (z >= nrel);
  const float* __restrict__ B = is_root ? R : (W + (size_t)(r0 + z) * K * BN);
  float* __restrict__ C = is_root ? Cden : (Hc + (size_t)z * M * BN);
  const int m0 = blockIdx.x * BM;

  __shared__ float As[BK][BM + 1];   // transposed A tile
  __shared__ float Bs[BK][BN];

  const int tid = threadIdx.x;
  const int tx = tid & 15;
  const int ty = tid >> 4;

  float acc[4][8];
#pragma unroll
  for (int i = 0; i < 4; ++i)
#pragma unroll
    for (int j = 0; j < 8; ++j) acc[i][j] = 0.f;

  for (int k0 = 0; k0 < K; k0 += BK) {
#pragma unroll
    for (int p2 = 0; p2 < 2; ++p2) {
      int f = tid + p2 * 256;
      int row = f >> 3;
      int colc = (f & 7) << 2;
      int ar = m0 + row; ar = ar < M ? ar : M - 1;
      float4 v = *(const float4*)(A + (size_t)ar * K + k0 + colc);
      As[colc + 0][row] = v.x;
      As[colc + 1][row] = v.y;
      As[colc + 2][row] = v.z;
      As[colc + 3][row] = v.w;
    }
#pragma unroll
    for (int p2 = 0; p2 < 4; ++p2) {
      int f = tid + p2 * 256;
      int row = f >> 5;
      int colc = (f & 31) << 2;
      *(float4*)&Bs[row][colc] = *(const float4*)(B + (size_t)(k0 + row) * BN + colc);
    }
    __syncthreads();

#pragma unroll
    for (int k = 0; k < BK; ++k) {
      float aa[4] = {As[k][ty * 4 + 0], As[k][ty * 4 + 1],
                     As[k][ty * 4 + 2], As[k][ty * 4 + 3]};
      float4 b0 = *(float4*)&Bs[k][tx * 8];
      float4 b1 = *(float4*)&Bs[k][tx * 8 + 4];
      float bb[8] = {b0.x, b0.y, b0.z, b0.w, b1.x, b1.y, b1.z, b1.w};
#pragma unroll
      for (int i = 0; i < 4; ++i)
#pragma unroll
        for (int j = 0; j < 8; ++j) acc[i][j] += aa[i] * bb[j];
    }
    __syncthreads();
  }

  float bv[8];
#pragma unroll
  for (int j = 0; j < 8; ++j) bv[j] = 0.f;
  if (is_root) {
#pragma unroll
    for (int j = 0; j < 8; ++j) bv[j] = bias[tx * 8 + j];
  }

#pragma unroll
  for (int i = 0; i < 4; ++i) {
    int r = m0 + ty * 4 + i;
    if (r < M) {
      float4 o0 = {acc[i][0] + bv[0], acc[i][1] + bv[1], acc[i][2] + bv[2], acc[i][3] + bv[3]};
      float4 o1 = {acc[i][4] + bv[4], acc[i][5] + bv[5], acc[i][6] + bv[6], acc[i][7] + bv[7]};
      *(float4*)(C + (size_t)r * BN + tx * 8) = o0;
      *(float4*)(C + (size_t)r * BN + tx * 8 + 4) = o1;
    }
  }
}

// ---------------- CSR build ----------------
__global__ void count_edges(const int* __restrict__ ei, const int* __restrict__ et,
                            int* __restrict__ deg, int* __restrict__ cnt) {
  int e = blockIdx.x * 256 + threadIdx.x;
  if (e >= N_EDGES) return;
  int d = ei[N_EDGES + e];
  int r = et[e];
  atomicAdd(&deg[d], 1);
  atomicAdd(&cnt[r * N_NODES + d], 1);
}

__global__ void inv_counts(const int* __restrict__ cnt, float* __restrict__ inv) {
  int i = blockIdx.x * 256 + threadIdx.x;
  if (i < N_REL * N_NODES) {
    int c = cnt[i];
    inv[i] = 1.0f / (float)(c > 1 ? c : 1);
  }
}

__global__ __launch_bounds__(1024) void scan_deg(const int* __restrict__ deg,
                                                 int* __restrict__ row_ptr,
                                                 int* __restrict__ cursor) {
  __shared__ int buf[1024];
  __shared__ int carry;
  if (threadIdx.x == 0) carry = 0;
  __syncthreads();
  for (int base = 0; base < N_NODES; base += 1024) {
    int i = base + threadIdx.x;
    int x = (i < N_NODES) ? deg[i] : 0;
    buf[threadIdx.x] = x;
    __syncthreads();
#pragma unroll
    for (int off = 1; off < 1024; off <<= 1) {
      int t = (threadIdx.x >= off) ? buf[threadIdx.x - off] : 0;
      __syncthreads();
      buf[threadIdx.x] += t;
      __syncthreads();
    }
    int incl = buf[threadIdx.x];
    int excl = incl - x;
    if (i < N_NODES) {
      int rp = carry + excl;
      row_ptr[i] = rp;
      cursor[i] = rp;
    }
    __syncthreads();
    if (threadIdx.x == 1023) carry += incl;
    __syncthreads();
  }
  if (threadIdx.x == 0) row_ptr[N_NODES] = carry;
}

__global__ void scatter_edges(const int* __restrict__ ei, const int* __restrict__ et,
                              int* __restrict__ cursor, unsigned int* __restrict__ csr) {
  int e = blockIdx.x * 256 + threadIdx.x;
  if (e >= N_EDGES) return;
  int s = ei[e];
  int d = ei[N_EDGES + e];
  int r = et[e];
  int pos = atomicAdd(&cursor[d], 1);
  csr[pos] = ((unsigned)r << 16) | (unsigned)s;   // src < 2^16, rel < 16
}

__global__ void count_graphs(const int* __restrict__ batch, int* __restrict__ gcnt) {
  int i = blockIdx.x * 256 + threadIdx.x;
  if (i < N_NODES) atomicAdd(&gcnt[batch[i]], 1);
}

// ---------------- aggregation (gather over a relation chunk) ----------------
__global__ __launch_bounds__(128) void aggregate(
    const float* __restrict__ Hc,       // [rc,M,128]
    const float* __restrict__ inv_cnt,  // [12,M]
    const int* __restrict__ row_ptr,
    const unsigned int* __restrict__ csr,
    float* __restrict__ h_out,          // [M,128], accumulated in place
    int r0, int rc, int do_relu)
{
  const int v = blockIdx.x;
  const int c = threadIdx.x;
  float acc = h_out[(size_t)v * D_H + c];
  const int e0 = row_ptr[v];
  const int e1 = row_ptr[v + 1];
  for (int e = e0; e < e1; ++e) {
    unsigned pk = csr[e];
    int r = (int)(pk >> 16) - r0;
    if ((unsigned)r < (unsigned)rc) {
      int src = pk & 0xFFFF;
      float w = inv_cnt[(r + r0) * N_NODES + v];
      acc += Hc[((size_t)r * N_NODES + src) * D_H + c] * w;
    }
  }
  if (do_relu) acc = fmaxf(acc, 0.f);
  h_out[(size_t)v * D_H + c] = acc;
}

// ---------------- final head/tail gather ----------------
__global__ __launch_bounds__(256) void final_gather(
    const float* __restrict__ h, const int* __restrict__ gcnt,
    const int* __restrict__ ih, const int* __restrict__ it,
    float* __restrict__ out)
{
  __shared__ int off_s;
  int g = blockIdx.x;
  if (threadIdx.x == 0) {
    int off = 0;
    for (int j = 0; j < g; ++j) off += gcnt[j];
    off_s = off;
  }
  __syncthreads();
  int off = off_s;
  int c = threadIdx.x;
  int hi = ih[g] + off;
  int ti = it[g] + off;
  out[(size_t)g * 256 + c] = (c < D_H) ? h[(size_t)hi * D_H + c]
                                       : h[(size_t)ti * D_H + (c - D_H)];
}

extern "C" void kernel_launch(void* const* d_in, const int* in_sizes, int n_in,
                              void* d_out, int out_size, void* d_ws, size_t ws_size,
                              hipStream_t stream) {
  const float* x   = (const float*)d_in[0];
  const int* ei    = (const int*)d_in[1];
  const int* et    = (const int*)d_in[2];
  const int* batch = (const int*)d_in[3];
  const int* ih    = (const int*)d_in[4];
  const int* it    = (const int*)d_in[5];
  const float* Wl[5]; const float* Rl[5]; const float* Bl[5];
  for (int l = 0; l < 5; ++l) {
    Wl[l] = (const float*)d_in[6 + 3 * l];
    Rl[l] = (const float*)d_in[7 + 3 * l];
    Bl[l] = (const float*)d_in[8 + 3 * l];
  }

  char* p = (char*)d_ws;
  size_t used = 0;
  auto alloc = [&](size_t bytes) {
    char* r = p;
    size_t rb = (bytes + 255) & ~(size_t)255;
    p += rb; used += rb;
    return r;
  };
  const size_t HREL = (size_t)N_NODES * D_H * 4;         // 25.6 MB per relation
  float* h_a    = (float*)alloc(HREL);
  float* h_b    = (float*)alloc(HREL);
  float* inv    = (float*)alloc((size_t)N_REL * N_NODES * 4);
  int* cnt      = (int*)alloc((size_t)N_REL * N_NODES * 4);
  int* deg      = (int*)alloc((size_t)N_NODES * 4);
  int* rowp     = (int*)alloc((size_t)(N_NODES + 1) * 4);
  int* cursor   = (int*)alloc((size_t)N_NODES * 4);
  unsigned* csr = (unsigned*)alloc((size_t)N_EDGES * 4);
  int* gcnt     = (int*)alloc((size_t)N_GRAPH * 4);

  // Relation-chunk buffer: as many relations as fit in the remaining ws.
  size_t remain = (ws_size > used) ? (ws_size - used) : 0;
  int RC = (int)(remain / HREL);
  if (RC > N_REL) RC = N_REL;
  if (RC < 1) RC = 1;                 // last resort; needs ~90 MB total
  float* Hc = (float*)alloc((size_t)RC * HREL);

  hipMemsetAsync(cnt, 0, (size_t)N_REL * N_NODES * 4, stream);
  hipMemsetAsync(deg, 0, (size_t)N_NODES * 4, stream);
  hipMemsetAsync(gcnt, 0, (size_t)N_GRAPH * 4, stream);

  count_edges<<<(N_EDGES + 255) / 256, 256, 0, stream>>>(ei, et, deg, cnt);
  inv_counts<<<(N_REL * N_NODES + 255) / 256, 256, 0, stream>>>(cnt, inv);
  scan_deg<<<1, 1024, 0, stream>>>(deg, rowp, cursor);
  scatter_edges<<<(N_EDGES + 255) / 256, 256, 0, stream>>>(ei, et, cursor, csr);
  count_graphs<<<(N_NODES + 255) / 256, 256, 0, stream>>>(batch, gcnt);

  const int gx = (N_NODES + BM - 1) / BM;
  for (int l = 0; l < 5; ++l) {
    const float* hin = (l == 0) ? x : ((l % 2 == 1) ? h_a : h_b);
    float* hout = (l % 2 == 0) ? h_a : h_b;
    int K = (l == 0) ? D_IN : D_H;
    int nchunks = (N_REL + RC - 1) / RC;
    for (int ch = 0; ch < nchunks; ++ch) {
      int r0 = ch * RC;
      int rc = (N_REL - r0) < RC ? (N_REL - r0) : RC;
      int zdim = rc + (ch == 0 ? 1 : 0);   // include root GEMM in first chunk
      dim3 grid(gx, 1, zdim);
      gemm_rgcn<<<grid, 256, 0, stream>>>(hin, Wl[l], Rl[l], Bl[l], Hc, hout,
                                          N_NODES, K, r0, rc);
      int relu = (l < 4 && ch == nchunks - 1) ? 1 : 0;
      aggregate<<<N_NODES, 128, 0, stream>>>(Hc, inv, rowp, csr, hout, r0, rc, relu);
    }
  }

  final_gather<<<N_GRAPH, 256, 0, stream>>>(h_a, gcnt, ih, it, (float*)d_out);
}

// Round 3
// 2590.758 us; speedup vs baseline: 1.6170x; 1.6170x over previous
//
#include <hip/hip_runtime.h>
#include <hip/hip_bf16.h>

// RGCN v3: GEMMs moved to MFMA (fp16 hi/lo split, 3 MFMAs per product ~ fp32
// precision). Aggregation/CSR path unchanged from v2 (adaptive relation-chunk).

#define N_NODES 50000
#define N_EDGES 800000
#define N_REL   12
#define D_IN    768
#define D_H     128
#define N_GRAPH 64

#define BMM   128   // GEMM tile M
#define KSTEP 32
#define LDA   40    // padded LDS row (fp16 elems): 80B, 16B-aligned, 2-way banks

typedef _Float16 f16x8 __attribute__((ext_vector_type(8)));
typedef _Float16 f16x4 __attribute__((ext_vector_type(4)));
typedef float    f32x4v __attribute__((ext_vector_type(4)));

// ---------------- fp32 -> (hi,lo) fp16 split, x4 vectorized ----------------
__global__ __launch_bounds__(256) void split_f32(
    const float* __restrict__ in, _Float16* __restrict__ hi,
    _Float16* __restrict__ lo, int n4)   // n4 = n/4
{
  int i = blockIdx.x * 256 + threadIdx.x;
  if (i >= n4) return;
  float4 v = *(const float4*)(in + (size_t)i * 4);
  f16x4 h, l;
  h[0] = (_Float16)v.x; l[0] = (_Float16)(v.x - (float)h[0]);
  h[1] = (_Float16)v.y; l[1] = (_Float16)(v.y - (float)h[1]);
  h[2] = (_Float16)v.z; l[2] = (_Float16)(v.z - (float)h[2]);
  h[3] = (_Float16)v.w; l[3] = (_Float16)(v.w - (float)h[3]);
  *(f16x4*)(hi + (size_t)i * 4) = h;
  *(f16x4*)(lo + (size_t)i * 4) = l;
}

// ---- weights: W[12][K][128] + R[K][128] -> transposed split [13][128][K] ----
__global__ __launch_bounds__(256) void wsplit(
    const float* __restrict__ W, const float* __restrict__ Rm,
    _Float16* __restrict__ th, _Float16* __restrict__ tl, int K)
{
  int idx = blockIdx.x * 256 + threadIdx.x;
  int total = 13 * 128 * K;
  if (idx >= total) return;
  int z = idx / (128 * K);
  int rem = idx - z * 128 * K;
  int n = rem / K;
  int k = rem - n * K;
  float v = (z < N_REL) ? W[((size_t)z * K + k) * 128 + n] : Rm[(size_t)k * 128 + n];
  _Float16 h = (_Float16)v;
  th[idx] = h;
  tl[idx] = (_Float16)(v - (float)h);
}

// ---------------- MFMA GEMM: C[M,128] = A[M,K] @ B[K,128] ----------------
// 1D grid nwg = zdim * mtiles, bijective XCD swizzle, m-tile-major logical
// order (13 z-blocks of one m-tile land on the same XCD -> A-strip L2 reuse).
__global__ __launch_bounds__(256, 2) void gemm_mfma(
    const _Float16* __restrict__ Ah, const _Float16* __restrict__ Al,  // [M][K]
    const _Float16* __restrict__ Wth, const _Float16* __restrict__ Wtl,// [13][128][K]
    const float* __restrict__ bias,
    float* __restrict__ Hc,            // [rc][M][128]
    float* __restrict__ Cden,          // [M][128]
    int M, int K, int r0, int rc, int zdim, int nwg)
{
  __shared__ _Float16 lds[4 * BMM * LDA];   // 40 KB
  _Float16* Ah_s = lds;
  _Float16* Al_s = lds + BMM * LDA;
  _Float16* Bh_s = lds + 2 * BMM * LDA;
  _Float16* Bl_s = lds + 3 * BMM * LDA;

  // bijective XCD swizzle (m204)
  int b = blockIdx.x;
  int q = nwg >> 3, rr = nwg & 7;
  int xcd = b & 7, ix = b >> 3;
  int wg = (xcd < rr ? xcd * (q + 1) : rr * (q + 1) + (xcd - rr) * q) + ix;
  int mt = wg / zdim;
  int z  = wg - mt * zdim;
  const bool is_root = (z >= rc);
  const int m0 = mt * BMM;

  const size_t wsel = (size_t)(is_root ? N_REL : (r0 + z)) * 128 * K;
  const _Float16* __restrict__ bh_src = Wth + wsel;
  const _Float16* __restrict__ bl_src = Wtl + wsel;

  const int t = threadIdx.x;
  const int lane = t & 63;
  const int wave = t >> 6;
  const int wr = wave >> 1, wc = wave & 1;   // 2x2 wave grid, 64x64 each
  const int l16 = lane & 15, kq = lane >> 4;

  f32x4v acc[4][4];
#pragma unroll
  for (int i = 0; i < 4; ++i)
#pragma unroll
    for (int j = 0; j < 4; ++j) acc[i][j] = (f32x4v){0.f, 0.f, 0.f, 0.f};

  for (int k0 = 0; k0 < K; k0 += KSTEP) {
    // stage 4 tiles of 128x32 fp16 (8KB each): 2 x 16B per thread per tile
#pragma unroll
    for (int p = 0; p < 2; ++p) {
      int f = t + p * 256;
      int row = f >> 2;
      int sg = (f & 3) << 3;
      int ar = m0 + row; ar = ar < M ? ar : M - 1;
      *(f16x8*)&Ah_s[row * LDA + sg] = *(const f16x8*)(Ah + (size_t)ar * K + k0 + sg);
      *(f16x8*)&Al_s[row * LDA + sg] = *(const f16x8*)(Al + (size_t)ar * K + k0 + sg);
      *(f16x8*)&Bh_s[row * LDA + sg] = *(const f16x8*)(bh_src + (size_t)row * K + k0 + sg);
      *(f16x8*)&Bl_s[row * LDA + sg] = *(const f16x8*)(bl_src + (size_t)row * K + k0 + sg);
    }
    __syncthreads();

    f16x8 ah[4], al[4], bh[4], bl[4];
#pragma unroll
    for (int i = 0; i < 4; ++i) {
      int ra = (wr * 64 + i * 16 + l16) * LDA + kq * 8;
      ah[i] = *(const f16x8*)&Ah_s[ra];
      al[i] = *(const f16x8*)&Al_s[ra];
      int rb = (wc * 64 + i * 16 + l16) * LDA + kq * 8;
      bh[i] = *(const f16x8*)&Bh_s[rb];
      bl[i] = *(const f16x8*)&Bl_s[rb];
    }
#pragma unroll
    for (int i = 0; i < 4; ++i)
#pragma unroll
      for (int j = 0; j < 4; ++j) {
        acc[i][j] = __builtin_amdgcn_mfma_f32_16x16x32_f16(ah[i], bh[j], acc[i][j], 0, 0, 0);
        acc[i][j] = __builtin_amdgcn_mfma_f32_16x16x32_f16(al[i], bh[j], acc[i][j], 0, 0, 0);
        acc[i][j] = __builtin_amdgcn_mfma_f32_16x16x32_f16(ah[i], bl[j], acc[i][j], 0, 0, 0);
      }
    __syncthreads();
  }

  float* __restrict__ C = is_root ? Cden : (Hc + (size_t)z * M * 128);
#pragma unroll
  for (int j = 0; j < 4; ++j) {
    int col = wc * 64 + j * 16 + l16;
    float bv = is_root ? bias[col] : 0.f;
#pragma unroll
    for (int i = 0; i < 4; ++i) {
#pragma unroll
      for (int rg = 0; rg < 4; ++rg) {
        int grow = m0 + wr * 64 + i * 16 + kq * 4 + rg;
        if (grow < M) C[(size_t)grow * 128 + col] = acc[i][j][rg] + bv;
      }
    }
  }
}

// ---------------- CSR build ----------------
__global__ void count_edges(const int* __restrict__ ei, const int* __restrict__ et,
                            int* __restrict__ deg, int* __restrict__ cnt) {
  int e = blockIdx.x * 256 + threadIdx.x;
  if (e >= N_EDGES) return;
  int d = ei[N_EDGES + e];
  int r = et[e];
  atomicAdd(&deg[d], 1);
  atomicAdd(&cnt[r * N_NODES + d], 1);
}

__global__ void inv_counts(const int* __restrict__ cnt, float* __restrict__ inv) {
  int i = blockIdx.x * 256 + threadIdx.x;
  if (i < N_REL * N_NODES) {
    int c = cnt[i];
    inv[i] = 1.0f / (float)(c > 1 ? c : 1);
  }
}

__global__ __launch_bounds__(1024) void scan_deg(const int* __restrict__ deg,
                                                 int* __restrict__ row_ptr,
                                                 int* __restrict__ cursor) {
  __shared__ int buf[1024];
  __shared__ int carry;
  if (threadIdx.x == 0) carry = 0;
  __syncthreads();
  for (int base = 0; base < N_NODES; base += 1024) {
    int i = base + threadIdx.x;
    int x = (i < N_NODES) ? deg[i] : 0;
    buf[threadIdx.x] = x;
    __syncthreads();
#pragma unroll
    for (int off = 1; off < 1024; off <<= 1) {
      int t = (threadIdx.x >= off) ? buf[threadIdx.x - off] : 0;
      __syncthreads();
      buf[threadIdx.x] += t;
      __syncthreads();
    }
    int incl = buf[threadIdx.x];
    int excl = incl - x;
    if (i < N_NODES) {
      int rp = carry + excl;
      row_ptr[i] = rp;
      cursor[i] = rp;
    }
    __syncthreads();
    if (threadIdx.x == 1023) carry += incl;
    __syncthreads();
  }
  if (threadIdx.x == 0) row_ptr[N_NODES] = carry;
}

__global__ void scatter_edges(const int* __restrict__ ei, const int* __restrict__ et,
                              int* __restrict__ cursor, unsigned int* __restrict__ csr) {
  int e = blockIdx.x * 256 + threadIdx.x;
  if (e >= N_EDGES) return;
  int s = ei[e];
  int d = ei[N_EDGES + e];
  int r = et[e];
  int pos = atomicAdd(&cursor[d], 1);
  csr[pos] = ((unsigned)r << 16) | (unsigned)s;   // src < 2^16, rel < 16
}

__global__ void count_graphs(const int* __restrict__ batch, int* __restrict__ gcnt) {
  int i = blockIdx.x * 256 + threadIdx.x;
  if (i < N_NODES) atomicAdd(&gcnt[batch[i]], 1);
}

// ---------------- aggregation (gather over a relation chunk) ----------------
__global__ __launch_bounds__(128) void aggregate(
    const float* __restrict__ Hc,       // [rc,M,128]
    const float* __restrict__ inv_cnt,  // [12,M]
    const int* __restrict__ row_ptr,
    const unsigned int* __restrict__ csr,
    float* __restrict__ h_out,          // [M,128], accumulated in place
    int r0, int rc, int do_relu)
{
  const int v = blockIdx.x;
  const int c = threadIdx.x;
  float acc = h_out[(size_t)v * D_H + c];
  const int e0 = row_ptr[v];
  const int e1 = row_ptr[v + 1];
  for (int e = e0; e < e1; ++e) {
    unsigned pk = csr[e];
    int r = (int)(pk >> 16) - r0;
    if ((unsigned)r < (unsigned)rc) {
      int src = pk & 0xFFFF;
      float w = inv_cnt[(r + r0) * N_NODES + v];
      acc += Hc[((size_t)r * N_NODES + src) * D_H + c] * w;
    }
  }
  if (do_relu) acc = fmaxf(acc, 0.f);
  h_out[(size_t)v * D_H + c] = acc;
}

// ---------------- final head/tail gather ----------------
__global__ __launch_bounds__(256) void final_gather(
    const float* __restrict__ h, const int* __restrict__ gcnt,
    const int* __restrict__ ih, const int* __restrict__ it,
    float* __restrict__ out)
{
  __shared__ int off_s;
  int g = blockIdx.x;
  if (threadIdx.x == 0) {
    int off = 0;
    for (int j = 0; j < g; ++j) off += gcnt[j];
    off_s = off;
  }
  __syncthreads();
  int off = off_s;
  int c = threadIdx.x;
  int hi = ih[g] + off;
  int ti = it[g] + off;
  out[(size_t)g * 256 + c] = (c < D_H) ? h[(size_t)hi * D_H + c]
                                       : h[(size_t)ti * D_H + (c - D_H)];
}

extern "C" void kernel_launch(void* const* d_in, const int* in_sizes, int n_in,
                              void* d_out, int out_size, void* d_ws, size_t ws_size,
                              hipStream_t stream) {
  (void)in_sizes; (void)n_in; (void)out_size;
  const float* x   = (const float*)d_in[0];
  const int* ei    = (const int*)d_in[1];
  const int* et    = (const int*)d_in[2];
  const int* batch = (const int*)d_in[3];
  const int* ih    = (const int*)d_in[4];
  const int* it    = (const int*)d_in[5];
  const float* Wl[5]; const float* Rl[5]; const float* Bl[5];
  for (int l = 0; l < 5; ++l) {
    Wl[l] = (const float*)d_in[6 + 3 * l];
    Rl[l] = (const float*)d_in[7 + 3 * l];
    Bl[l] = (const float*)d_in[8 + 3 * l];
  }

  char* p = (char*)d_ws;
  size_t used = 0;
  auto alloc = [&](size_t bytes) {
    char* r = p;
    size_t rb = (bytes + 255) & ~(size_t)255;
    p += rb; used += rb;
    return r;
  };
  const size_t HREL = (size_t)N_NODES * D_H * 4;   // 25.6 MB per relation (fp32)
  float* h_a      = (float*)alloc(HREL);
  float* h_b      = (float*)alloc(HREL);
  _Float16* Ahb   = (_Float16*)alloc((size_t)N_NODES * D_IN * 2);  // 76.8 MB
  _Float16* Alb   = (_Float16*)alloc((size_t)N_NODES * D_IN * 2);  // 76.8 MB
  _Float16* Wth   = (_Float16*)alloc((size_t)13 * 128 * D_IN * 2); // 2.6 MB
  _Float16* Wtl   = (_Float16*)alloc((size_t)13 * 128 * D_IN * 2);
  float* inv      = (float*)alloc((size_t)N_REL * N_NODES * 4);
  int* cnt        = (int*)alloc((size_t)N_REL * N_NODES * 4);
  int* deg        = (int*)alloc((size_t)N_NODES * 4);
  int* rowp       = (int*)alloc((size_t)(N_NODES + 1) * 4);
  int* cursor     = (int*)alloc((size_t)N_NODES * 4);
  unsigned* csr   = (unsigned*)alloc((size_t)N_EDGES * 4);
  int* gcnt       = (int*)alloc((size_t)N_GRAPH * 4);

  size_t remain = (ws_size > used) ? (ws_size - used) : 0;
  int RC = (int)(remain / HREL);
  if (RC > N_REL) RC = N_REL;
  if (RC < 1) RC = 1;
  float* Hc = (float*)alloc((size_t)RC * HREL);

  hipMemsetAsync(cnt, 0, (size_t)N_REL * N_NODES * 4, stream);
  hipMemsetAsync(deg, 0, (size_t)N_NODES * 4, stream);
  hipMemsetAsync(gcnt, 0, (size_t)N_GRAPH * 4, stream);

  count_edges<<<(N_EDGES + 255) / 256, 256, 0, stream>>>(ei, et, deg, cnt);
  inv_counts<<<(N_REL * N_NODES + 255) / 256, 256, 0, stream>>>(cnt, inv);
  scan_deg<<<1, 1024, 0, stream>>>(deg, rowp, cursor);
  scatter_edges<<<(N_EDGES + 255) / 256, 256, 0, stream>>>(ei, et, cursor, csr);
  count_graphs<<<(N_NODES + 255) / 256, 256, 0, stream>>>(batch, gcnt);

  const int mtiles = (N_NODES + BMM - 1) / BMM;   // 391
  for (int l = 0; l < 5; ++l) {
    const float* hin = (l == 0) ? x : ((l % 2 == 1) ? h_a : h_b);
    float* hout = (l % 2 == 0) ? h_a : h_b;
    int K = (l == 0) ? D_IN : D_H;

    int n4 = N_NODES * K / 4;
    split_f32<<<(n4 + 255) / 256, 256, 0, stream>>>(hin, Ahb, Alb, n4);
    int wtot = 13 * 128 * K;
    wsplit<<<(wtot + 255) / 256, 256, 0, stream>>>(Wl[l], Rl[l], Wth, Wtl, K);

    int nchunks = (N_REL + RC - 1) / RC;
    for (int ch = 0; ch < nchunks; ++ch) {
      int r0 = ch * RC;
      int rc = (N_REL - r0) < RC ? (N_REL - r0) : RC;
      int zdim = rc + (ch == 0 ? 1 : 0);   // include root GEMM in first chunk
      int nwg = zdim * mtiles;
      gemm_mfma<<<nwg, 256, 0, stream>>>(Ahb, Alb, Wth, Wtl, Bl[l], Hc, hout,
                                         N_NODES, K, r0, rc, zdim, nwg);
      int relu = (l < 4 && ch == nchunks - 1) ? 1 : 0;
      aggregate<<<N_NODES, 128, 0, stream>>>(Hc, inv, rowp, csr, hout, r0, rc, relu);
    }
  }

  final_gather<<<N_GRAPH, 256, 0, stream>>>(h_a, gcnt, ih, it, (float*)d_out);
}

// Round 6
// 2063.748 us; speedup vs baseline: 2.0299x; 1.2554x over previous
//
#include <hip/hip_runtime.h>
#include <hip/hip_bf16.h>

// RGCN v5: v4b with the fp16 epilogue copy-loop mapping fixed
// (row = flat>>4, c16 = (flat&15)*8 — was flat>>3/(flat&7), which read LDS OOB
// and scribbled neighboring m-tiles' rows -> NaN).

#define N_NODES 50000
#define N_EDGES 800000
#define N_REL   12
#define D_IN    768
#define D_H     128
#define N_GRAPH 64

#define BMM   128   // GEMM tile M
#define KSTEP 32
#define LDA   40    // padded LDS row (fp16 elems) for staging tiles
#define LDC   136   // padded LDS row (fp16 elems) for epilogue C-stage

typedef _Float16 f16x8 __attribute__((ext_vector_type(8)));
typedef _Float16 f16x4 __attribute__((ext_vector_type(4)));
typedef float    f32x4v __attribute__((ext_vector_type(4)));
typedef unsigned int u32x4 __attribute__((ext_vector_type(4)));

// ---------------- fp32 -> (hi,lo) fp16 split, x4 vectorized ----------------
__global__ __launch_bounds__(256) void split_f32(
    const float* __restrict__ in, _Float16* __restrict__ hi,
    _Float16* __restrict__ lo, int n4)
{
  int i = blockIdx.x * 256 + threadIdx.x;
  if (i >= n4) return;
  float4 v = *(const float4*)(in + (size_t)i * 4);
  f16x4 h, l;
  h[0] = (_Float16)v.x; l[0] = (_Float16)(v.x - (float)h[0]);
  h[1] = (_Float16)v.y; l[1] = (_Float16)(v.y - (float)h[1]);
  h[2] = (_Float16)v.z; l[2] = (_Float16)(v.z - (float)h[2]);
  h[3] = (_Float16)v.w; l[3] = (_Float16)(v.w - (float)h[3]);
  *(f16x4*)(hi + (size_t)i * 4) = h;
  *(f16x4*)(lo + (size_t)i * 4) = l;
}

// ---- weights: W[12][K][128] + R[K][128] -> transposed split [13][128][K] ----
__global__ __launch_bounds__(256) void wsplit(
    const float* __restrict__ W, const float* __restrict__ Rm,
    _Float16* __restrict__ th, _Float16* __restrict__ tl, int K)
{
  int idx = blockIdx.x * 256 + threadIdx.x;
  int total = 13 * 128 * K;
  if (idx >= total) return;
  int z = idx / (128 * K);
  int rem = idx - z * 128 * K;
  int n = rem / K;
  int k = rem - n * K;
  float v = (z < N_REL) ? W[((size_t)z * K + k) * 128 + n] : Rm[(size_t)k * 128 + n];
  _Float16 h = (_Float16)v;
  th[idx] = h;
  tl[idx] = (_Float16)(v - (float)h);
}

// ---------------- MFMA GEMM ----------------
// z < rc: Hc16[z] = A @ W[r0+z]  (fp16 out, nt stores via LDS stage)
// z >= rc: Cden = A @ R + bias   (fp32 out)
__global__ __launch_bounds__(256, 3) void gemm_mfma(
    const _Float16* __restrict__ Ah, const _Float16* __restrict__ Al,  // [M][K]
    const _Float16* __restrict__ Wth, const _Float16* __restrict__ Wtl,// [13][128][K]
    const float* __restrict__ bias,
    _Float16* __restrict__ Hc,         // [rc][M][128] fp16
    float* __restrict__ Cden,          // [M][128] fp32
    int M, int K, int r0, int rc, int zdim, int nwg)
{
  __shared__ _Float16 lds[4 * BMM * LDA];   // 40960 B; reused as Cs[128][LDC] (34816 B)
  _Float16* Ah_s = lds;
  _Float16* Al_s = lds + BMM * LDA;
  _Float16* Bh_s = lds + 2 * BMM * LDA;
  _Float16* Bl_s = lds + 3 * BMM * LDA;

  // bijective XCD swizzle (m204); logical order m-tile-major so the 13 z-blocks
  // of one m-tile are consecutive on one XCD -> A-strip L2 reuse.
  int b = blockIdx.x;
  int q = nwg >> 3, rr = nwg & 7;
  int xcd = b & 7, ix = b >> 3;
  int wg = (xcd < rr ? xcd * (q + 1) : rr * (q + 1) + (xcd - rr) * q) + ix;
  int mt = wg / zdim;
  int z  = wg - mt * zdim;
  const bool is_root = (z >= rc);
  const int m0 = mt * BMM;

  const size_t wsel = (size_t)(is_root ? N_REL : (r0 + z)) * 128 * K;
  const _Float16* __restrict__ bh_src = Wth + wsel;
  const _Float16* __restrict__ bl_src = Wtl + wsel;

  const int t = threadIdx.x;
  const int lane = t & 63;
  const int wave = t >> 6;
  const int wr = wave >> 1, wc = wave & 1;   // 2x2 wave grid, 64x64 each
  const int l16 = lane & 15, kq = lane >> 4;

  f32x4v acc[4][4];
#pragma unroll
  for (int i = 0; i < 4; ++i)
#pragma unroll
    for (int j = 0; j < 4; ++j) acc[i][j] = (f32x4v){0.f, 0.f, 0.f, 0.f};

  for (int k0 = 0; k0 < K; k0 += KSTEP) {
#pragma unroll
    for (int p = 0; p < 2; ++p) {
      int f = t + p * 256;
      int row = f >> 2;
      int sg = (f & 3) << 3;
      int ar = m0 + row; ar = ar < M ? ar : M - 1;
      *(f16x8*)&Ah_s[row * LDA + sg] = *(const f16x8*)(Ah + (size_t)ar * K + k0 + sg);
      *(f16x8*)&Al_s[row * LDA + sg] = *(const f16x8*)(Al + (size_t)ar * K + k0 + sg);
      *(f16x8*)&Bh_s[row * LDA + sg] = *(const f16x8*)(bh_src + (size_t)row * K + k0 + sg);
      *(f16x8*)&Bl_s[row * LDA + sg] = *(const f16x8*)(bl_src + (size_t)row * K + k0 + sg);
    }
    __syncthreads();

    f16x8 ah[4], al[4], bh[4], bl[4];
#pragma unroll
    for (int i = 0; i < 4; ++i) {
      int ra = (wr * 64 + i * 16 + l16) * LDA + kq * 8;
      ah[i] = *(const f16x8*)&Ah_s[ra];
      al[i] = *(const f16x8*)&Al_s[ra];
      int rb = (wc * 64 + i * 16 + l16) * LDA + kq * 8;
      bh[i] = *(const f16x8*)&Bh_s[rb];
      bl[i] = *(const f16x8*)&Bl_s[rb];
    }
#pragma unroll
    for (int i = 0; i < 4; ++i)
#pragma unroll
      for (int j = 0; j < 4; ++j) {
        acc[i][j] = __builtin_amdgcn_mfma_f32_16x16x32_f16(ah[i], bh[j], acc[i][j], 0, 0, 0);
        acc[i][j] = __builtin_amdgcn_mfma_f32_16x16x32_f16(al[i], bh[j], acc[i][j], 0, 0, 0);
        acc[i][j] = __builtin_amdgcn_mfma_f32_16x16x32_f16(ah[i], bl[j], acc[i][j], 0, 0, 0);
      }
    __syncthreads();
  }

  if (is_root) {
    // fp32 output + bias, scalar nt stores (64B segments per quarter-wave)
#pragma unroll
    for (int j = 0; j < 4; ++j) {
      int col = wc * 64 + j * 16 + l16;
      float bv = bias[col];
#pragma unroll
      for (int i = 0; i < 4; ++i)
#pragma unroll
        for (int rg = 0; rg < 4; ++rg) {
          int grow = m0 + wr * 64 + i * 16 + kq * 4 + rg;
          if (grow < M)
            __builtin_nontemporal_store(acc[i][j][rg] + bv,
                                        Cden + (size_t)grow * 128 + col);
        }
    }
  } else {
    // stage fp16 tile in LDS, then fully-coalesced 16B nt stores
    _Float16* Cs = lds;
#pragma unroll
    for (int i = 0; i < 4; ++i)
#pragma unroll
      for (int j = 0; j < 4; ++j)
#pragma unroll
        for (int rg = 0; rg < 4; ++rg) {
          int lr = wr * 64 + i * 16 + kq * 4 + rg;
          int lc = wc * 64 + j * 16 + l16;
          Cs[lr * LDC + lc] = (_Float16)acc[i][j][rg];
        }
    __syncthreads();
    _Float16* __restrict__ Crel = Hc + (size_t)z * M * 128;
#pragma unroll
    for (int p = 0; p < 8; ++p) {
      int flat = t + 256 * p;          // 0..2047 -> 128 rows x 16 chunks x 16B
      int row = flat >> 4;
      int c16 = (flat & 15) * 8;
      int gr = m0 + row;
      if (gr < M) {
        u32x4 v = *(const u32x4*)&Cs[row * LDC + c16];
        __builtin_nontemporal_store(v, (u32x4*)(Crel + (size_t)gr * 128 + c16));
      }
    }
  }
}

// ---------------- CSR build ----------------
__global__ void count_edges(const int* __restrict__ ei, const int* __restrict__ et,
                            int* __restrict__ deg, int* __restrict__ cnt) {
  int e = blockIdx.x * 256 + threadIdx.x;
  if (e >= N_EDGES) return;
  int d = ei[N_EDGES + e];
  int r = et[e];
  atomicAdd(&deg[d], 1);
  atomicAdd(&cnt[r * N_NODES + d], 1);
}

__global__ void inv_counts(const int* __restrict__ cnt, float* __restrict__ inv) {
  int i = blockIdx.x * 256 + threadIdx.x;
  if (i < N_REL * N_NODES) {
    int c = cnt[i];
    inv[i] = 1.0f / (float)(c > 1 ? c : 1);
  }
}

__global__ __launch_bounds__(1024) void scan_deg(const int* __restrict__ deg,
                                                 int* __restrict__ row_ptr,
                                                 int* __restrict__ cursor) {
  __shared__ int buf[1024];
  __shared__ int carry;
  if (threadIdx.x == 0) carry = 0;
  __syncthreads();
  for (int base = 0; base < N_NODES; base += 1024) {
    int i = base + threadIdx.x;
    int x = (i < N_NODES) ? deg[i] : 0;
    buf[threadIdx.x] = x;
    __syncthreads();
#pragma unroll
    for (int off = 1; off < 1024; off <<= 1) {
      int t = (threadIdx.x >= off) ? buf[threadIdx.x - off] : 0;
      __syncthreads();
      buf[threadIdx.x] += t;
      __syncthreads();
    }
    int incl = buf[threadIdx.x];
    int excl = incl - x;
    if (i < N_NODES) {
      int rp = carry + excl;
      row_ptr[i] = rp;
      cursor[i] = rp;
    }
    __syncthreads();
    if (threadIdx.x == 1023) carry += incl;
    __syncthreads();
  }
  if (threadIdx.x == 0) row_ptr[N_NODES] = carry;
}

__global__ void scatter_edges(const int* __restrict__ ei, const int* __restrict__ et,
                              int* __restrict__ cursor, unsigned int* __restrict__ csr) {
  int e = blockIdx.x * 256 + threadIdx.x;
  if (e >= N_EDGES) return;
  int s = ei[e];
  int d = ei[N_EDGES + e];
  int r = et[e];
  int pos = atomicAdd(&cursor[d], 1);
  csr[pos] = ((unsigned)r << 16) | (unsigned)s;   // src < 2^16, rel < 16
}

__global__ void count_graphs(const int* __restrict__ batch, int* __restrict__ gcnt) {
  int i = blockIdx.x * 256 + threadIdx.x;
  if (i < N_NODES) atomicAdd(&gcnt[batch[i]], 1);
}

// ------------- aggregation: one wave per node, lane = 2 cols -------------
__global__ __launch_bounds__(256) void aggregate(
    const _Float16* __restrict__ Hc,    // [rc,M,128] fp16
    const float* __restrict__ inv_cnt,  // [12,M]
    const int* __restrict__ row_ptr,
    const unsigned int* __restrict__ csr,
    float* __restrict__ h_out,          // [M,128], accumulated in place
    int r0, int rc, int do_relu)
{
  const int v = blockIdx.x * 4 + (threadIdx.x >> 6);
  if (v >= N_NODES) return;
  const int lane = threadIdx.x & 63;
  float2 acc = *(const float2*)&h_out[(size_t)v * D_H + lane * 2];
  const int e0 = row_ptr[v];
  const int e1 = row_ptr[v + 1];
  for (int e = e0; e < e1; ++e) {
    unsigned pk = csr[e];
    int r = (int)(pk >> 16) - r0;
    if ((unsigned)r < (unsigned)rc) {
      int src = pk & 0xFFFF;
      float w = inv_cnt[(r + r0) * N_NODES + v];
      const _Float16* hp = Hc + ((size_t)r * N_NODES + src) * D_H + lane * 2;
      acc.x += (float)hp[0] * w;
      acc.y += (float)hp[1] * w;
    }
  }
  if (do_relu) { acc.x = fmaxf(acc.x, 0.f); acc.y = fmaxf(acc.y, 0.f); }
  *(float2*)&h_out[(size_t)v * D_H + lane * 2] = acc;
}

// ---------------- final head/tail gather ----------------
__global__ __launch_bounds__(256) void final_gather(
    const float* __restrict__ h, const int* __restrict__ gcnt,
    const int* __restrict__ ih, const int* __restrict__ it,
    float* __restrict__ out)
{
  __shared__ int off_s;
  int g = blockIdx.x;
  if (threadIdx.x == 0) {
    int off = 0;
    for (int j = 0; j < g; ++j) off += gcnt[j];
    off_s = off;
  }
  __syncthreads();
  int off = off_s;
  int c = threadIdx.x;
  int hi = ih[g] + off;
  int ti = it[g] + off;
  out[(size_t)g * 256 + c] = (c < D_H) ? h[(size_t)hi * D_H + c]
                                       : h[(size_t)ti * D_H + (c - D_H)];
}

extern "C" void kernel_launch(void* const* d_in, const int* in_sizes, int n_in,
                              void* d_out, int out_size, void* d_ws, size_t ws_size,
                              hipStream_t stream) {
  (void)in_sizes; (void)n_in; (void)out_size;
  const float* x   = (const float*)d_in[0];
  const int* ei    = (const int*)d_in[1];
  const int* et    = (const int*)d_in[2];
  const int* batch = (const int*)d_in[3];
  const int* ih    = (const int*)d_in[4];
  const int* it    = (const int*)d_in[5];
  const float* Wl[5]; const float* Rl[5]; const float* Bl[5];
  for (int l = 0; l < 5; ++l) {
    Wl[l] = (const float*)d_in[6 + 3 * l];
    Rl[l] = (const float*)d_in[7 + 3 * l];
    Bl[l] = (const float*)d_in[8 + 3 * l];
  }

  char* p = (char*)d_ws;
  size_t used = 0;
  auto alloc = [&](size_t bytes) {
    char* r = p;
    size_t rb = (bytes + 255) & ~(size_t)255;
    p += rb; used += rb;
    return r;
  };
  const size_t HREL16 = (size_t)N_NODES * D_H * 2;   // 12.8 MB per relation (fp16)
  float* h_a      = (float*)alloc((size_t)N_NODES * D_H * 4);
  float* h_b      = (float*)alloc((size_t)N_NODES * D_H * 4);
  _Float16* Ahb   = (_Float16*)alloc((size_t)N_NODES * D_IN * 2);  // 76.8 MB
  _Float16* Alb   = (_Float16*)alloc((size_t)N_NODES * D_IN * 2);  // 76.8 MB
  _Float16* Wth   = (_Float16*)alloc((size_t)13 * 128 * D_IN * 2); // 2.6 MB
  _Float16* Wtl   = (_Float16*)alloc((size_t)13 * 128 * D_IN * 2);
  float* inv      = (float*)alloc((size_t)N_REL * N_NODES * 4);
  int* cnt        = (int*)alloc((size_t)N_REL * N_NODES * 4);
  int* deg        = (int*)alloc((size_t)N_NODES * 4);
  int* rowp       = (int*)alloc((size_t)(N_NODES + 1) * 4);
  int* cursor     = (int*)alloc((size_t)N_NODES * 4);
  unsigned* csr   = (unsigned*)alloc((size_t)N_EDGES * 4);
  int* gcnt       = (int*)alloc((size_t)N_GRAPH * 4);

  size_t remain = (ws_size > used) ? (ws_size - used) : 0;
  int RC = (int)(remain / HREL16);
  if (RC > N_REL) RC = N_REL;
  if (RC < 1) RC = 1;
  _Float16* Hc = (_Float16*)alloc((size_t)RC * HREL16);

  hipMemsetAsync(cnt, 0, (size_t)N_REL * N_NODES * 4, stream);
  hipMemsetAsync(deg, 0, (size_t)N_NODES * 4, stream);
  hipMemsetAsync(gcnt, 0, (size_t)N_GRAPH * 4, stream);

  count_edges<<<(N_EDGES + 255) / 256, 256, 0, stream>>>(ei, et, deg, cnt);
  inv_counts<<<(N_REL * N_NODES + 255) / 256, 256, 0, stream>>>(cnt, inv);
  scan_deg<<<1, 1024, 0, stream>>>(deg, rowp, cursor);
  scatter_edges<<<(N_EDGES + 255) / 256, 256, 0, stream>>>(ei, et, cursor, csr);
  count_graphs<<<(N_NODES + 255) / 256, 256, 0, stream>>>(batch, gcnt);

  const int mtiles = (N_NODES + BMM - 1) / BMM;   // 391
  for (int l = 0; l < 5; ++l) {
    const float* hin = (l == 0) ? x : ((l % 2 == 1) ? h_a : h_b);
    float* hout = (l % 2 == 0) ? h_a : h_b;
    int K = (l == 0) ? D_IN : D_H;

    int n4 = N_NODES * K / 4;
    split_f32<<<(n4 + 255) / 256, 256, 0, stream>>>(hin, Ahb, Alb, n4);
    int wtot = 13 * 128 * K;
    wsplit<<<(wtot + 255) / 256, 256, 0, stream>>>(Wl[l], Rl[l], Wth, Wtl, K);

    int nchunks = (N_REL + RC - 1) / RC;
    for (int ch = 0; ch < nchunks; ++ch) {
      int r0 = ch * RC;
      int rc = (N_REL - r0) < RC ? (N_REL - r0) : RC;
      int zdim = rc + (ch == 0 ? 1 : 0);   // include root GEMM in first chunk
      int nwg = zdim * mtiles;
      gemm_mfma<<<nwg, 256, 0, stream>>>(Ahb, Alb, Wth, Wtl, Bl[l], Hc, hout,
                                         N_NODES, K, r0, rc, zdim, nwg);
      int relu = (l < 4 && ch == nchunks - 1) ? 1 : 0;
      aggregate<<<(N_NODES + 3) / 4, 256, 0, stream>>>(Hc, inv, rowp, csr, hout,
                                                       r0, rc, relu);
    }
  }

  final_gather<<<N_GRAPH, 256, 0, stream>>>(h_a, gcnt, ih, it, (float*)d_out);
}

// Round 8
// 1840.779 us; speedup vs baseline: 2.2758x; 1.1211x over previous
//
#include <hip/hip_runtime.h>
#include <hip/hip_bf16.h>

// RGCN v6 (resubmit — R7 was an infra timeout, kernel never ran):
//          (a) 2-MFMA scheme (split A only; W kept fp16 — err ~2e-4 << 6.5e-3 thr)
//          (b) global_load_lds width-16 staging, linear LDS, m97 2-barrier K-loop
//          (c) 24 KB LDS (3 tiles), epilogue in two 64-row half-passes
//          (d) aggregate: u32 row gathers + per-edge precomputed weight,
//              writes next layer's (Ah,Al) directly (split kernels deleted for l>0)

#define N_NODES 50000
#define N_EDGES 800000
#define N_REL   12
#define D_IN    768
#define D_H     128
#define N_GRAPH 64

#define BMM   128
#define KSTEP 32
#define LDC   136   // padded fp16 row for epilogue C-stage

typedef _Float16 f16x8 __attribute__((ext_vector_type(8)));
typedef _Float16 f16x4 __attribute__((ext_vector_type(4)));
typedef float    f32x4v __attribute__((ext_vector_type(4)));
typedef unsigned int u32x4 __attribute__((ext_vector_type(4)));

#define GLDS16(g, l) __builtin_amdgcn_global_load_lds( \
    (const __attribute__((address_space(1))) unsigned int*)(g), \
    (__attribute__((address_space(3))) unsigned int*)(l), 16, 0, 0)

// ---------------- fp32 -> (hi,lo) fp16 split (layer 0 input only) -----------
__global__ __launch_bounds__(256) void split_f32(
    const float* __restrict__ in, _Float16* __restrict__ hi,
    _Float16* __restrict__ lo, int n4)
{
  int i = blockIdx.x * 256 + threadIdx.x;
  if (i >= n4) return;
  float4 v = *(const float4*)(in + (size_t)i * 4);
  f16x4 h, l;
  h[0] = (_Float16)v.x; l[0] = (_Float16)(v.x - (float)h[0]);
  h[1] = (_Float16)v.y; l[1] = (_Float16)(v.y - (float)h[1]);
  h[2] = (_Float16)v.z; l[2] = (_Float16)(v.z - (float)h[2]);
  h[3] = (_Float16)v.w; l[3] = (_Float16)(v.w - (float)h[3]);
  *(f16x4*)(hi + (size_t)i * 4) = h;
  *(f16x4*)(lo + (size_t)i * 4) = l;
}

// ---- weights: W[12][K][128] + R[K][128] -> transposed fp16 [13][128][K] ----
__global__ __launch_bounds__(256) void wsplit(
    const float* __restrict__ W, const float* __restrict__ Rm,
    _Float16* __restrict__ th, int K)
{
  int idx = blockIdx.x * 256 + threadIdx.x;
  int total = 13 * 128 * K;
  if (idx >= total) return;
  int z = idx / (128 * K);
  int rem = idx - z * 128 * K;
  int n = rem / K;
  int k = rem - n * K;
  float v = (z < N_REL) ? W[((size_t)z * K + k) * 128 + n] : Rm[(size_t)k * 128 + n];
  th[idx] = (_Float16)v;
}

// ---------------- MFMA GEMM (m97-style: glds + 2 barriers per K-step) -------
// z < rc: Hc[z] = (Ah+Al) @ Wh[r0+z]  (fp16 out via LDS-staged nt stores)
// z >= rc: Cden = (Ah+Al) @ Wh[12] + bias (fp32 out)
__global__ __launch_bounds__(256, 3) void gemm_mfma(
    const _Float16* __restrict__ Ah, const _Float16* __restrict__ Al,  // [M][K]
    const _Float16* __restrict__ Wh,   // [13][128][K]
    const float* __restrict__ bias,
    _Float16* __restrict__ Hc,         // [rc][M][128] fp16
    float* __restrict__ Cden,          // [M][128] fp32
    int M, int K, int r0, int rc, int zdim, int nwg)
{
  __shared__ _Float16 lds[3 * BMM * KSTEP];   // 24576 B, linear tiles
  _Float16* Ah_s = lds;
  _Float16* Al_s = lds + BMM * KSTEP;
  _Float16* B_s  = lds + 2 * BMM * KSTEP;

  // bijective XCD swizzle, m-tile-major logical order
  int b = blockIdx.x;
  int q = nwg >> 3, rr = nwg & 7;
  int xcd = b & 7, ix = b >> 3;
  int wg = (xcd < rr ? xcd * (q + 1) : rr * (q + 1) + (xcd - rr) * q) + ix;
  int mt = wg / zdim;
  int z  = wg - mt * zdim;
  const bool is_root = (z >= rc);
  const int m0 = mt * BMM;

  const _Float16* __restrict__ b_src =
      Wh + (size_t)(is_root ? N_REL : (r0 + z)) * 128 * K;

  const int t = threadIdx.x;
  const int lane = t & 63;
  const int wave = t >> 6;
  const int wr = wave >> 1, wc = wave & 1;   // 2x2 wave grid, 64x64 each
  const int l16 = lane & 15, kq = lane >> 4;

  // staging: tile = 128x32 f16 = 512 x 16B chunks; wave w covers chunks
  // [w*128, w*128+128) in two glds issues (64 chunks = 1 KB each).
  const int c0 = wave * 128 + lane;
  const int c1 = c0 + 64;
  const int cr0 = c0 >> 2, cs0 = (c0 & 3) << 3;
  const int cr1 = c1 >> 2, cs1 = (c1 & 3) << 3;
  int a0 = m0 + cr0; a0 = a0 < M ? a0 : M - 1;
  int a1 = m0 + cr1; a1 = a1 < M ? a1 : M - 1;
  const _Float16* gAh0 = Ah + (size_t)a0 * K + cs0;
  const _Float16* gAh1 = Ah + (size_t)a1 * K + cs1;
  const _Float16* gAl0 = Al + (size_t)a0 * K + cs0;
  const _Float16* gAl1 = Al + (size_t)a1 * K + cs1;
  const _Float16* gB0  = b_src + (size_t)cr0 * K + cs0;
  const _Float16* gB1  = b_src + (size_t)cr1 * K + cs1;
  _Float16* dAh = Ah_s + wave * 1024;   // wave-uniform LDS dest (lane x 16B)
  _Float16* dAl = Al_s + wave * 1024;
  _Float16* dB  = B_s  + wave * 1024;

  f32x4v acc[4][4];
#pragma unroll
  for (int i = 0; i < 4; ++i)
#pragma unroll
    for (int j = 0; j < 4; ++j) acc[i][j] = (f32x4v){0.f, 0.f, 0.f, 0.f};

  for (int k0 = 0; k0 < K; k0 += KSTEP) {
    GLDS16(gAh0 + k0, dAh);
    GLDS16(gAh1 + k0, dAh + 512);
    GLDS16(gAl0 + k0, dAl);
    GLDS16(gAl1 + k0, dAl + 512);
    GLDS16(gB0  + k0, dB);
    GLDS16(gB1  + k0, dB + 512);
    __syncthreads();   // drains vmcnt -> tiles ready

    f16x8 fah[4], fal[4], fb[4];
#pragma unroll
    for (int i = 0; i < 4; ++i) {
      int ra = (wr * 64 + i * 16 + l16) * KSTEP + kq * 8;
      fah[i] = *(const f16x8*)&Ah_s[ra];
      fal[i] = *(const f16x8*)&Al_s[ra];
      int rb = (wc * 64 + i * 16 + l16) * KSTEP + kq * 8;
      fb[i]  = *(const f16x8*)&B_s[rb];
    }
#pragma unroll
    for (int i = 0; i < 4; ++i)
#pragma unroll
      for (int j = 0; j < 4; ++j) {
        acc[i][j] = __builtin_amdgcn_mfma_f32_16x16x32_f16(fah[i], fb[j], acc[i][j], 0, 0, 0);
        acc[i][j] = __builtin_amdgcn_mfma_f32_16x16x32_f16(fal[i], fb[j], acc[i][j], 0, 0, 0);
      }
    __syncthreads();   // all reads done before next iter's glds lands
  }

  if (is_root) {
#pragma unroll
    for (int j = 0; j < 4; ++j) {
      int col = wc * 64 + j * 16 + l16;
      float bv = bias[col];
#pragma unroll
      for (int i = 0; i < 4; ++i)
#pragma unroll
        for (int rg = 0; rg < 4; ++rg) {
          int grow = m0 + wr * 64 + i * 16 + kq * 4 + rg;
          if (grow < M)
            __builtin_nontemporal_store(acc[i][j][rg] + bv,
                                        Cden + (size_t)grow * 128 + col);
        }
    }
  } else {
    // two 64-row half-passes through a [64][LDC] fp16 stage (17.4 KB < 24 KB)
    _Float16* Cs = lds;
    _Float16* __restrict__ Crel = Hc + (size_t)z * M * 128;
#pragma unroll
    for (int h = 0; h < 2; ++h) {
      if (wr == h) {
#pragma unroll
        for (int i = 0; i < 4; ++i)
#pragma unroll
          for (int j = 0; j < 4; ++j)
#pragma unroll
            for (int rg = 0; rg < 4; ++rg)
              Cs[(i * 16 + kq * 4 + rg) * LDC + wc * 64 + j * 16 + l16] =
                  (_Float16)acc[i][j][rg];
      }
      __syncthreads();
#pragma unroll
      for (int p = 0; p < 4; ++p) {
        int q2 = t + 256 * p;          // 0..1023 -> 64 rows x 16 chunks
        int row = q2 >> 4, c16 = (q2 & 15) * 8;
        int gr = m0 + h * 64 + row;
        if (gr < M) {
          u32x4 v = *(const u32x4*)&Cs[row * LDC + c16];
          __builtin_nontemporal_store(v, (u32x4*)(Crel + (size_t)gr * 128 + c16));
        }
      }
      __syncthreads();
    }
  }
}

// ---------------- CSR build ----------------
__global__ void count_edges(const int* __restrict__ ei, const int* __restrict__ et,
                            int* __restrict__ deg, int* __restrict__ cnt) {
  int e = blockIdx.x * 256 + threadIdx.x;
  if (e >= N_EDGES) return;
  int d = ei[N_EDGES + e];
  int r = et[e];
  atomicAdd(&deg[d], 1);
  atomicAdd(&cnt[r * N_NODES + d], 1);
}

__global__ void inv_counts(const int* __restrict__ cnt, float* __restrict__ inv) {
  int i = blockIdx.x * 256 + threadIdx.x;
  if (i < N_REL * N_NODES) {
    int c = cnt[i];
    inv[i] = 1.0f / (float)(c > 1 ? c : 1);
  }
}

__global__ __launch_bounds__(1024) void scan_deg(const int* __restrict__ deg,
                                                 int* __restrict__ row_ptr,
                                                 int* __restrict__ cursor) {
  __shared__ int buf[1024];
  __shared__ int carry;
  if (threadIdx.x == 0) carry = 0;
  __syncthreads();
  for (int base = 0; base < N_NODES; base += 1024) {
    int i = base + threadIdx.x;
    int x = (i < N_NODES) ? deg[i] : 0;
    buf[threadIdx.x] = x;
    __syncthreads();
#pragma unroll
    for (int off = 1; off < 1024; off <<= 1) {
      int t = (threadIdx.x >= off) ? buf[threadIdx.x - off] : 0;
      __syncthreads();
      buf[threadIdx.x] += t;
      __syncthreads();
    }
    int incl = buf[threadIdx.x];
    int excl = incl - x;
    if (i < N_NODES) {
      int rp = carry + excl;
      row_ptr[i] = rp;
      cursor[i] = rp;
    }
    __syncthreads();
    if (threadIdx.x == 1023) carry += incl;
    __syncthreads();
  }
  if (threadIdx.x == 0) row_ptr[N_NODES] = carry;
}

__global__ void scatter_edges(const int* __restrict__ ei, const int* __restrict__ et,
                              const float* __restrict__ inv,
                              int* __restrict__ cursor,
                              unsigned int* __restrict__ csr_pk,
                              float* __restrict__ csr_w) {
  int e = blockIdx.x * 256 + threadIdx.x;
  if (e >= N_EDGES) return;
  int s = ei[e];
  int d = ei[N_EDGES + e];
  int r = et[e];
  int pos = atomicAdd(&cursor[d], 1);
  csr_pk[pos] = ((unsigned)r << 16) | (unsigned)s;   // src < 2^16, rel < 16
  csr_w[pos] = inv[r * N_NODES + d];
}

__global__ void count_graphs(const int* __restrict__ batch, int* __restrict__ gcnt) {
  int i = blockIdx.x * 256 + threadIdx.x;
  if (i < N_NODES) atomicAdd(&gcnt[batch[i]], 1);
}

// --------- aggregation: wave per node, lane = 1 u32 (2 fp16 cols) ----------
// reads fp32 base h (root result / running sum), adds chunk messages;
// write_split: emit next layer's (Ah,Al) fp16; write_f32: keep fp32 h.
__global__ __launch_bounds__(256) void aggregate(
    const _Float16* __restrict__ Hc,    // [rc][N][128] fp16
    const int* __restrict__ row_ptr,
    const unsigned int* __restrict__ csr_pk,
    const float* __restrict__ csr_w,
    float* __restrict__ h,              // [N][128] fp32, in/out
    _Float16* __restrict__ AhO, _Float16* __restrict__ AlO,
    int r0, int rc, int do_relu, int write_split, int write_f32)
{
  const int v = blockIdx.x * 4 + (threadIdx.x >> 6);
  if (v >= N_NODES) return;
  const int lane = threadIdx.x & 63;
  float2 acc = *(const float2*)&h[(size_t)v * 128 + lane * 2];
  const int e0 = row_ptr[v];
  const int e1 = row_ptr[v + 1];
  for (int e = e0; e < e1; ++e) {
    unsigned pk = csr_pk[e];
    int r = (int)(pk >> 16) - r0;
    if ((unsigned)r < (unsigned)rc) {
      int src = pk & 0xFFFF;
      float w = csr_w[e];
      unsigned pv = *((const unsigned*)(Hc + ((size_t)r * N_NODES + src) * 128) + lane);
      union { unsigned u; _Float16 f[2]; } cv; cv.u = pv;
      acc.x += w * (float)cv.f[0];
      acc.y += w * (float)cv.f[1];
    }
  }
  if (do_relu) { acc.x = fmaxf(acc.x, 0.f); acc.y = fmaxf(acc.y, 0.f); }
  if (write_split) {
    union { _Float16 f[2]; unsigned u; } ph, pl;
    ph.f[0] = (_Float16)acc.x; ph.f[1] = (_Float16)acc.y;
    pl.f[0] = (_Float16)(acc.x - (float)ph.f[0]);
    pl.f[1] = (_Float16)(acc.y - (float)ph.f[1]);
    ((unsigned*)AhO)[(size_t)v * 64 + lane] = ph.u;
    ((unsigned*)AlO)[(size_t)v * 64 + lane] = pl.u;
  }
  if (write_f32) *(float2*)&h[(size_t)v * 128 + lane * 2] = acc;
}

// ---------------- final head/tail gather ----------------
__global__ __launch_bounds__(256) void final_gather(
    const float* __restrict__ h, const int* __restrict__ gcnt,
    const int* __restrict__ ih, const int* __restrict__ it,
    float* __restrict__ out)
{
  __shared__ int off_s;
  int g = blockIdx.x;
  if (threadIdx.x == 0) {
    int off = 0;
    for (int j = 0; j < g; ++j) off += gcnt[j];
    off_s = off;
  }
  __syncthreads();
  int off = off_s;
  int c = threadIdx.x;
  int hi = ih[g] + off;
  int ti = it[g] + off;
  out[(size_t)g * 256 + c] = (c < D_H) ? h[(size_t)hi * D_H + c]
                                       : h[(size_t)ti * D_H + (c - D_H)];
}

extern "C" void kernel_launch(void* const* d_in, const int* in_sizes, int n_in,
                              void* d_out, int out_size, void* d_ws, size_t ws_size,
                              hipStream_t stream) {
  (void)in_sizes; (void)n_in; (void)out_size;
  const float* x   = (const float*)d_in[0];
  const int* ei    = (const int*)d_in[1];
  const int* et    = (const int*)d_in[2];
  const int* batch = (const int*)d_in[3];
  const int* ih    = (const int*)d_in[4];
  const int* it    = (const int*)d_in[5];
  const float* Wl[5]; const float* Rl[5]; const float* Bl[5];
  for (int l = 0; l < 5; ++l) {
    Wl[l] = (const float*)d_in[6 + 3 * l];
    Rl[l] = (const float*)d_in[7 + 3 * l];
    Bl[l] = (const float*)d_in[8 + 3 * l];
  }

  char* p = (char*)d_ws;
  size_t used = 0;
  auto alloc = [&](size_t bytes) {
    char* r = p;
    size_t rb = (bytes + 255) & ~(size_t)255;
    p += rb; used += rb;
    return r;
  };
  const size_t HREL16 = (size_t)N_NODES * D_H * 2;   // 12.8 MB per relation
  float* h        = (float*)alloc((size_t)N_NODES * D_H * 4);      // 25.6 MB
  _Float16* Ahb   = (_Float16*)alloc((size_t)N_NODES * D_IN * 2);  // 76.8 MB
  _Float16* Alb   = (_Float16*)alloc((size_t)N_NODES * D_IN * 2);  // 76.8 MB
  _Float16* Wh    = (_Float16*)alloc((size_t)13 * 128 * D_IN * 2); // 2.6 MB
  float* inv      = (float*)alloc((size_t)N_REL * N_NODES * 4);
  int* cnt        = (int*)alloc((size_t)N_REL * N_NODES * 4);
  int* deg        = (int*)alloc((size_t)N_NODES * 4);
  int* rowp       = (int*)alloc((size_t)(N_NODES + 1) * 4);
  int* cursor     = (int*)alloc((size_t)N_NODES * 4);
  unsigned* csr_pk = (unsigned*)alloc((size_t)N_EDGES * 4);
  float* csr_w    = (float*)alloc((size_t)N_EDGES * 4);
  int* gcnt       = (int*)alloc((size_t)N_GRAPH * 4);

  size_t remain = (ws_size > used) ? (ws_size - used) : 0;
  int RC = (int)(remain / HREL16);
  if (RC > N_REL) RC = N_REL;
  if (RC < 1) RC = 1;
  _Float16* Hc = (_Float16*)alloc((size_t)RC * HREL16);

  hipMemsetAsync(cnt, 0, (size_t)N_REL * N_NODES * 4, stream);
  hipMemsetAsync(deg, 0, (size_t)N_NODES * 4, stream);
  hipMemsetAsync(gcnt, 0, (size_t)N_GRAPH * 4, stream);

  count_edges<<<(N_EDGES + 255) / 256, 256, 0, stream>>>(ei, et, deg, cnt);
  inv_counts<<<(N_REL * N_NODES + 255) / 256, 256, 0, stream>>>(cnt, inv);
  scan_deg<<<1, 1024, 0, stream>>>(deg, rowp, cursor);
  scatter_edges<<<(N_EDGES + 255) / 256, 256, 0, stream>>>(ei, et, inv, cursor,
                                                           csr_pk, csr_w);
  count_graphs<<<(N_NODES + 255) / 256, 256, 0, stream>>>(batch, gcnt);

  // layer-0 input split (only explicit split needed)
  int n4 = N_NODES * D_IN / 4;
  split_f32<<<(n4 + 255) / 256, 256, 0, stream>>>(x, Ahb, Alb, n4);

  const int mtiles = (N_NODES + BMM - 1) / BMM;   // 391
  for (int l = 0; l < 5; ++l) {
    int K = (l == 0) ? D_IN : D_H;
    int wtot = 13 * 128 * K;
    wsplit<<<(wtot + 255) / 256, 256, 0, stream>>>(Wl[l], Rl[l], Wh, K);

    int nchunks = (N_REL + RC - 1) / RC;
    for (int ch = 0; ch < nchunks; ++ch) {
      int r0 = ch * RC;
      int rc = (N_REL - r0) < RC ? (N_REL - r0) : RC;
      int zdim = rc + (ch == 0 ? 1 : 0);   // include root GEMM in first chunk
      int nwg = zdim * mtiles;
      gemm_mfma<<<nwg, 256, 0, stream>>>(Ahb, Alb, Wh, Bl[l], Hc, h,
                                         N_NODES, K, r0, rc, zdim, nwg);
      int final_ch = (ch == nchunks - 1);
      int relu  = (l < 4 && final_ch) ? 1 : 0;
      int wspl  = (l < 4 && final_ch) ? 1 : 0;
      int wf32  = (!final_ch || l == 4) ? 1 : 0;
      aggregate<<<(N_NODES + 3) / 4, 256, 0, stream>>>(Hc, rowp, csr_pk, csr_w,
                                                       h, Ahb, Alb,
                                                       r0, rc, relu, wspl, wf32);
    }
  }

  final_gather<<<N_GRAPH, 256, 0, stream>>>(h, gcnt, ih, it, (float*)d_out);
}

// Round 9
// 1641.900 us; speedup vs baseline: 2.5514x; 1.1211x over previous
//
#include <hip/hip_runtime.h>
#include <hip/hip_bf16.h>

// RGCN v7: aggregate rewritten — per-edge (offset,weight) packed u64, batch
// coalesced descriptor load + __shfl broadcast, gathers pipelined (no serial
// uniform-address loads). GEMM: __launch_bounds__(256,4). Rest = v6.

#define N_NODES 50000
#define N_EDGES 800000
#define N_REL   12
#define D_IN    768
#define D_H     128
#define N_GRAPH 64

#define BMM   128
#define KSTEP 32
#define LDC   136   // padded fp16 row for epilogue C-stage

typedef _Float16 f16x8 __attribute__((ext_vector_type(8)));
typedef _Float16 f16x4 __attribute__((ext_vector_type(4)));
typedef float    f32x4v __attribute__((ext_vector_type(4)));
typedef unsigned int u32x4 __attribute__((ext_vector_type(4)));

#define GLDS16(g, l) __builtin_amdgcn_global_load_lds( \
    (const __attribute__((address_space(1))) unsigned int*)(g), \
    (__attribute__((address_space(3))) unsigned int*)(l), 16, 0, 0)

// ---------------- fp32 -> (hi,lo) fp16 split (layer 0 input only) -----------
__global__ __launch_bounds__(256) void split_f32(
    const float* __restrict__ in, _Float16* __restrict__ hi,
    _Float16* __restrict__ lo, int n4)
{
  int i = blockIdx.x * 256 + threadIdx.x;
  if (i >= n4) return;
  float4 v = *(const float4*)(in + (size_t)i * 4);
  f16x4 h, l;
  h[0] = (_Float16)v.x; l[0] = (_Float16)(v.x - (float)h[0]);
  h[1] = (_Float16)v.y; l[1] = (_Float16)(v.y - (float)h[1]);
  h[2] = (_Float16)v.z; l[2] = (_Float16)(v.z - (float)h[2]);
  h[3] = (_Float16)v.w; l[3] = (_Float16)(v.w - (float)h[3]);
  *(f16x4*)(hi + (size_t)i * 4) = h;
  *(f16x4*)(lo + (size_t)i * 4) = l;
}

// ---- weights: W[12][K][128] + R[K][128] -> transposed fp16 [13][128][K] ----
__global__ __launch_bounds__(256) void wsplit(
    const float* __restrict__ W, const float* __restrict__ Rm,
    _Float16* __restrict__ th, int K)
{
  int idx = blockIdx.x * 256 + threadIdx.x;
  int total = 13 * 128 * K;
  if (idx >= total) return;
  int z = idx / (128 * K);
  int rem = idx - z * 128 * K;
  int n = rem / K;
  int k = rem - n * K;
  float v = (z < N_REL) ? W[((size_t)z * K + k) * 128 + n] : Rm[(size_t)k * 128 + n];
  th[idx] = (_Float16)v;
}

// ---------------- MFMA GEMM (glds + 2 barriers per K-step) ----------------
__global__ __launch_bounds__(256, 4) void gemm_mfma(
    const _Float16* __restrict__ Ah, const _Float16* __restrict__ Al,  // [M][K]
    const _Float16* __restrict__ Wh,   // [13][128][K]
    const float* __restrict__ bias,
    _Float16* __restrict__ Hc,         // [rc][M][128] fp16
    float* __restrict__ Cden,          // [M][128] fp32
    int M, int K, int r0, int rc, int zdim, int nwg)
{
  __shared__ _Float16 lds[3 * BMM * KSTEP];   // 24576 B
  _Float16* Ah_s = lds;
  _Float16* Al_s = lds + BMM * KSTEP;
  _Float16* B_s  = lds + 2 * BMM * KSTEP;

  // bijective XCD swizzle, m-tile-major logical order
  int b = blockIdx.x;
  int q = nwg >> 3, rr = nwg & 7;
  int xcd = b & 7, ix = b >> 3;
  int wg = (xcd < rr ? xcd * (q + 1) : rr * (q + 1) + (xcd - rr) * q) + ix;
  int mt = wg / zdim;
  int z  = wg - mt * zdim;
  const bool is_root = (z >= rc);
  const int m0 = mt * BMM;

  const _Float16* __restrict__ b_src =
      Wh + (size_t)(is_root ? N_REL : (r0 + z)) * 128 * K;

  const int t = threadIdx.x;
  const int lane = t & 63;
  const int wave = t >> 6;
  const int wr = wave >> 1, wc = wave & 1;   // 2x2 wave grid, 64x64 each
  const int l16 = lane & 15, kq = lane >> 4;

  const int c0 = wave * 128 + lane;
  const int c1 = c0 + 64;
  const int cr0 = c0 >> 2, cs0 = (c0 & 3) << 3;
  const int cr1 = c1 >> 2, cs1 = (c1 & 3) << 3;
  int a0 = m0 + cr0; a0 = a0 < M ? a0 : M - 1;
  int a1 = m0 + cr1; a1 = a1 < M ? a1 : M - 1;
  const _Float16* gAh0 = Ah + (size_t)a0 * K + cs0;
  const _Float16* gAh1 = Ah + (size_t)a1 * K + cs1;
  const _Float16* gAl0 = Al + (size_t)a0 * K + cs0;
  const _Float16* gAl1 = Al + (size_t)a1 * K + cs1;
  const _Float16* gB0  = b_src + (size_t)cr0 * K + cs0;
  const _Float16* gB1  = b_src + (size_t)cr1 * K + cs1;
  _Float16* dAh = Ah_s + wave * 1024;
  _Float16* dAl = Al_s + wave * 1024;
  _Float16* dB  = B_s  + wave * 1024;

  f32x4v acc[4][4];
#pragma unroll
  for (int i = 0; i < 4; ++i)
#pragma unroll
    for (int j = 0; j < 4; ++j) acc[i][j] = (f32x4v){0.f, 0.f, 0.f, 0.f};

  for (int k0 = 0; k0 < K; k0 += KSTEP) {
    GLDS16(gAh0 + k0, dAh);
    GLDS16(gAh1 + k0, dAh + 512);
    GLDS16(gAl0 + k0, dAl);
    GLDS16(gAl1 + k0, dAl + 512);
    GLDS16(gB0  + k0, dB);
    GLDS16(gB1  + k0, dB + 512);
    __syncthreads();

    f16x8 fah[4], fal[4], fb[4];
#pragma unroll
    for (int i = 0; i < 4; ++i) {
      int ra = (wr * 64 + i * 16 + l16) * KSTEP + kq * 8;
      fah[i] = *(const f16x8*)&Ah_s[ra];
      fal[i] = *(const f16x8*)&Al_s[ra];
      int rb = (wc * 64 + i * 16 + l16) * KSTEP + kq * 8;
      fb[i]  = *(const f16x8*)&B_s[rb];
    }
#pragma unroll
    for (int i = 0; i < 4; ++i)
#pragma unroll
      for (int j = 0; j < 4; ++j) {
        acc[i][j] = __builtin_amdgcn_mfma_f32_16x16x32_f16(fah[i], fb[j], acc[i][j], 0, 0, 0);
        acc[i][j] = __builtin_amdgcn_mfma_f32_16x16x32_f16(fal[i], fb[j], acc[i][j], 0, 0, 0);
      }
    __syncthreads();
  }

  if (is_root) {
#pragma unroll
    for (int j = 0; j < 4; ++j) {
      int col = wc * 64 + j * 16 + l16;
      float bv = bias[col];
#pragma unroll
      for (int i = 0; i < 4; ++i)
#pragma unroll
        for (int rg = 0; rg < 4; ++rg) {
          int grow = m0 + wr * 64 + i * 16 + kq * 4 + rg;
          if (grow < M)
            __builtin_nontemporal_store(acc[i][j][rg] + bv,
                                        Cden + (size_t)grow * 128 + col);
        }
    }
  } else {
    _Float16* Cs = lds;
    _Float16* __restrict__ Crel = Hc + (size_t)z * M * 128;
#pragma unroll
    for (int h = 0; h < 2; ++h) {
      if (wr == h) {
#pragma unroll
        for (int i = 0; i < 4; ++i)
#pragma unroll
          for (int j = 0; j < 4; ++j)
#pragma unroll
            for (int rg = 0; rg < 4; ++rg)
              Cs[(i * 16 + kq * 4 + rg) * LDC + wc * 64 + j * 16 + l16] =
                  (_Float16)acc[i][j][rg];
      }
      __syncthreads();
#pragma unroll
      for (int p = 0; p < 4; ++p) {
        int q2 = t + 256 * p;          // 64 rows x 16 chunks
        int row = q2 >> 4, c16 = (q2 & 15) * 8;
        int gr = m0 + h * 64 + row;
        if (gr < M) {
          u32x4 v = *(const u32x4*)&Cs[row * LDC + c16];
          __builtin_nontemporal_store(v, (u32x4*)(Crel + (size_t)gr * 128 + c16));
        }
      }
      __syncthreads();
    }
  }
}

// ---------------- CSR build ----------------
__global__ void count_edges(const int* __restrict__ ei, const int* __restrict__ et,
                            int* __restrict__ deg, int* __restrict__ cnt) {
  int e = blockIdx.x * 256 + threadIdx.x;
  if (e >= N_EDGES) return;
  int d = ei[N_EDGES + e];
  int r = et[e];
  atomicAdd(&deg[d], 1);
  atomicAdd(&cnt[r * N_NODES + d], 1);
}

__global__ void inv_counts(const int* __restrict__ cnt, float* __restrict__ inv) {
  int i = blockIdx.x * 256 + threadIdx.x;
  if (i < N_REL * N_NODES) {
    int c = cnt[i];
    inv[i] = 1.0f / (float)(c > 1 ? c : 1);
  }
}

__global__ __launch_bounds__(1024) void scan_deg(const int* __restrict__ deg,
                                                 int* __restrict__ row_ptr,
                                                 int* __restrict__ cursor) {
  __shared__ int buf[1024];
  __shared__ int carry;
  if (threadIdx.x == 0) carry = 0;
  __syncthreads();
  for (int base = 0; base < N_NODES; base += 1024) {
    int i = base + threadIdx.x;
    int x = (i < N_NODES) ? deg[i] : 0;
    buf[threadIdx.x] = x;
    __syncthreads();
#pragma unroll
    for (int off = 1; off < 1024; off <<= 1) {
      int t = (threadIdx.x >= off) ? buf[threadIdx.x - off] : 0;
      __syncthreads();
      buf[threadIdx.x] += t;
      __syncthreads();
    }
    int incl = buf[threadIdx.x];
    int excl = incl - x;
    if (i < N_NODES) {
      int rp = carry + excl;
      row_ptr[i] = rp;
      cursor[i] = rp;
    }
    __syncthreads();
    if (threadIdx.x == 1023) carry += incl;
    __syncthreads();
  }
  if (threadIdx.x == 0) row_ptr[N_NODES] = carry;
}

// pack per-edge {byte-offset into Hc, fp32 weight} as u64
__global__ void scatter_edges(const int* __restrict__ ei, const int* __restrict__ et,
                              const float* __restrict__ inv,
                              int* __restrict__ cursor,
                              unsigned long long* __restrict__ csr_ow) {
  int e = blockIdx.x * 256 + threadIdx.x;
  if (e >= N_EDGES) return;
  int s = ei[e];
  int d = ei[N_EDGES + e];
  int r = et[e];
  int pos = atomicAdd(&cursor[d], 1);
  unsigned off = ((unsigned)r * (unsigned)N_NODES + (unsigned)s) * 256u; // bytes
  float w = inv[r * N_NODES + d];
  union { float f; unsigned u; } wu; wu.f = w;
  csr_ow[pos] = (unsigned long long)off | ((unsigned long long)wu.u << 32);
}

__global__ void count_graphs(const int* __restrict__ batch, int* __restrict__ gcnt) {
  int i = blockIdx.x * 256 + threadIdx.x;
  if (i < N_NODES) atomicAdd(&gcnt[batch[i]], 1);
}

// ------- aggregation: wave/node; batch descriptor load + shfl broadcast -----
__global__ __launch_bounds__(256) void aggregate(
    const _Float16* __restrict__ Hc,    // [rc][N][128] fp16 (full when rc==12)
    const int* __restrict__ row_ptr,
    const unsigned long long* __restrict__ csr_ow,
    float* __restrict__ h,              // [N][128] fp32, in/out
    _Float16* __restrict__ AhO, _Float16* __restrict__ AlO,
    int r0, int rc, int do_relu, int write_split, int write_f32)
{
  const int v = blockIdx.x * 4 + (threadIdx.x >> 6);
  if (v >= N_NODES) return;
  const int lane = threadIdx.x & 63;
  float2 acc = *(const float2*)&h[(size_t)v * 128 + lane * 2];
  const int e0 = row_ptr[v];
  const int e1 = row_ptr[v + 1];
  const bool full = (rc == N_REL);
  const char* __restrict__ HcB = (const char*)Hc;

  for (int base = e0; base < e1; base += 64) {
    int n = e1 - base; n = n < 64 ? n : 64;
    int idx = base + lane; idx = idx < e1 ? idx : e1 - 1;
    unsigned long long ow = csr_ow[idx];       // coalesced 512B descriptor load
    unsigned off_l = (unsigned)ow;
    float w_l = __uint_as_float((unsigned)(ow >> 32));
    for (int i = 0; i < n; ++i) {
      unsigned off = (unsigned)__shfl((int)off_l, i);
      float w = __shfl(w_l, i);
      if (!full) {
        unsigned rowi = off >> 8;                       // r*N + src
        unsigned r = rowi / (unsigned)N_NODES;
        if (r - (unsigned)r0 >= (unsigned)rc) continue;
        off -= (unsigned)r0 * (unsigned)N_NODES * 256u;
      }
      unsigned pv = *((const unsigned*)(HcB + off) + lane);
      union { unsigned u; _Float16 f[2]; } cv; cv.u = pv;
      acc.x += w * (float)cv.f[0];
      acc.y += w * (float)cv.f[1];
    }
  }
  if (do_relu) { acc.x = fmaxf(acc.x, 0.f); acc.y = fmaxf(acc.y, 0.f); }
  if (write_split) {
    union { _Float16 f[2]; unsigned u; } ph, pl;
    ph.f[0] = (_Float16)acc.x; ph.f[1] = (_Float16)acc.y;
    pl.f[0] = (_Float16)(acc.x - (float)ph.f[0]);
    pl.f[1] = (_Float16)(acc.y - (float)ph.f[1]);
    ((unsigned*)AhO)[(size_t)v * 64 + lane] = ph.u;
    ((unsigned*)AlO)[(size_t)v * 64 + lane] = pl.u;
  }
  if (write_f32) *(float2*)&h[(size_t)v * 128 + lane * 2] = acc;
}

// ---------------- final head/tail gather ----------------
__global__ __launch_bounds__(256) void final_gather(
    const float* __restrict__ h, const int* __restrict__ gcnt,
    const int* __restrict__ ih, const int* __restrict__ it,
    float* __restrict__ out)
{
  __shared__ int off_s;
  int g = blockIdx.x;
  if (threadIdx.x == 0) {
    int off = 0;
    for (int j = 0; j < g; ++j) off += gcnt[j];
    off_s = off;
  }
  __syncthreads();
  int off = off_s;
  int c = threadIdx.x;
  int hi = ih[g] + off;
  int ti = it[g] + off;
  out[(size_t)g * 256 + c] = (c < D_H) ? h[(size_t)hi * D_H + c]
                                       : h[(size_t)ti * D_H + (c - D_H)];
}

extern "C" void kernel_launch(void* const* d_in, const int* in_sizes, int n_in,
                              void* d_out, int out_size, void* d_ws, size_t ws_size,
                              hipStream_t stream) {
  (void)in_sizes; (void)n_in; (void)out_size;
  const float* x   = (const float*)d_in[0];
  const int* ei    = (const int*)d_in[1];
  const int* et    = (const int*)d_in[2];
  const int* batch = (const int*)d_in[3];
  const int* ih    = (const int*)d_in[4];
  const int* it    = (const int*)d_in[5];
  const float* Wl[5]; const float* Rl[5]; const float* Bl[5];
  for (int l = 0; l < 5; ++l) {
    Wl[l] = (const float*)d_in[6 + 3 * l];
    Rl[l] = (const float*)d_in[7 + 3 * l];
    Bl[l] = (const float*)d_in[8 + 3 * l];
  }

  char* p = (char*)d_ws;
  size_t used = 0;
  auto alloc = [&](size_t bytes) {
    char* r = p;
    size_t rb = (bytes + 255) & ~(size_t)255;
    p += rb; used += rb;
    return r;
  };
  const size_t HREL16 = (size_t)N_NODES * D_H * 2;   // 12.8 MB per relation
  float* h        = (float*)alloc((size_t)N_NODES * D_H * 4);      // 25.6 MB
  _Float16* Ahb   = (_Float16*)alloc((size_t)N_NODES * D_IN * 2);  // 76.8 MB
  _Float16* Alb   = (_Float16*)alloc((size_t)N_NODES * D_IN * 2);  // 76.8 MB
  _Float16* Wh    = (_Float16*)alloc((size_t)13 * 128 * D_IN * 2); // 2.6 MB
  float* inv      = (float*)alloc((size_t)N_REL * N_NODES * 4);
  int* cnt        = (int*)alloc((size_t)N_REL * N_NODES * 4);
  int* deg        = (int*)alloc((size_t)N_NODES * 4);
  int* rowp       = (int*)alloc((size_t)(N_NODES + 1) * 4);
  int* cursor     = (int*)alloc((size_t)N_NODES * 4);
  unsigned long long* csr_ow = (unsigned long long*)alloc((size_t)N_EDGES * 8);
  int* gcnt       = (int*)alloc((size_t)N_GRAPH * 4);

  size_t remain = (ws_size > used) ? (ws_size - used) : 0;
  int RC = (int)(remain / HREL16);
  if (RC > N_REL) RC = N_REL;
  if (RC < 1) RC = 1;
  _Float16* Hc = (_Float16*)alloc((size_t)RC * HREL16);

  hipMemsetAsync(cnt, 0, (size_t)N_REL * N_NODES * 4, stream);
  hipMemsetAsync(deg, 0, (size_t)N_NODES * 4, stream);
  hipMemsetAsync(gcnt, 0, (size_t)N_GRAPH * 4, stream);

  count_edges<<<(N_EDGES + 255) / 256, 256, 0, stream>>>(ei, et, deg, cnt);
  inv_counts<<<(N_REL * N_NODES + 255) / 256, 256, 0, stream>>>(cnt, inv);
  scan_deg<<<1, 1024, 0, stream>>>(deg, rowp, cursor);
  scatter_edges<<<(N_EDGES + 255) / 256, 256, 0, stream>>>(ei, et, inv, cursor, csr_ow);
  count_graphs<<<(N_NODES + 255) / 256, 256, 0, stream>>>(batch, gcnt);

  // layer-0 input split
  int n4 = N_NODES * D_IN / 4;
  split_f32<<<(n4 + 255) / 256, 256, 0, stream>>>(x, Ahb, Alb, n4);

  const int mtiles = (N_NODES + BMM - 1) / BMM;   // 391
  for (int l = 0; l < 5; ++l) {
    int K = (l == 0) ? D_IN : D_H;
    int wtot = 13 * 128 * K;
    wsplit<<<(wtot + 255) / 256, 256, 0, stream>>>(Wl[l], Rl[l], Wh, K);

    int nchunks = (N_REL + RC - 1) / RC;
    for (int ch = 0; ch < nchunks; ++ch) {
      int r0 = ch * RC;
      int rc = (N_REL - r0) < RC ? (N_REL - r0) : RC;
      int zdim = rc + (ch == 0 ? 1 : 0);
      int nwg = zdim * mtiles;
      gemm_mfma<<<nwg, 256, 0, stream>>>(Ahb, Alb, Wh, Bl[l], Hc, h,
                                         N_NODES, K, r0, rc, zdim, nwg);
      int final_ch = (ch == nchunks - 1);
      int relu  = (l < 4 && final_ch) ? 1 : 0;
      int wspl  = (l < 4 && final_ch) ? 1 : 0;
      int wf32  = (!final_ch || l == 4) ? 1 : 0;
      aggregate<<<(N_NODES + 3) / 4, 256, 0, stream>>>(Hc, rowp, csr_ow,
                                                       h, Ahb, Alb,
                                                       r0, rc, relu, wspl, wf32);
    }
  }

  final_gather<<<N_GRAPH, 256, 0, stream>>>(h, gcnt, ih, it, (float*)d_out);
}

// Round 10
// 1370.765 us; speedup vs baseline: 3.0561x; 1.1978x over previous
//
#include <hip/hip_runtime.h>
#include <hip/hip_bf16.h>

// RGCN v8: aggregate — wave-uniform (readfirstlane) scalar descriptor loads
// (s_load, no shfl) + 4-deep manually pipelined gathers. scan_deg replaced by
// 3-kernel hierarchical scan. GEMM frozen from v7.

#define N_NODES 50000
#define N_EDGES 800000
#define N_REL   12
#define D_IN    768
#define D_H     128
#define N_GRAPH 64

#define BMM   128
#define KSTEP 32
#define LDC   136   // padded fp16 row for epilogue C-stage

#define SCAN_B 1024
#define SCAN_NB ((N_NODES + SCAN_B - 1) / SCAN_B)   // 49

typedef _Float16 f16x8 __attribute__((ext_vector_type(8)));
typedef _Float16 f16x4 __attribute__((ext_vector_type(4)));
typedef float    f32x4v __attribute__((ext_vector_type(4)));
typedef unsigned int u32x4 __attribute__((ext_vector_type(4)));

#define GLDS16(g, l) __builtin_amdgcn_global_load_lds( \
    (const __attribute__((address_space(1))) unsigned int*)(g), \
    (__attribute__((address_space(3))) unsigned int*)(l), 16, 0, 0)

// ---------------- fp32 -> (hi,lo) fp16 split (layer 0 input only) -----------
__global__ __launch_bounds__(256) void split_f32(
    const float* __restrict__ in, _Float16* __restrict__ hi,
    _Float16* __restrict__ lo, int n4)
{
  int i = blockIdx.x * 256 + threadIdx.x;
  if (i >= n4) return;
  float4 v = *(const float4*)(in + (size_t)i * 4);
  f16x4 h, l;
  h[0] = (_Float16)v.x; l[0] = (_Float16)(v.x - (float)h[0]);
  h[1] = (_Float16)v.y; l[1] = (_Float16)(v.y - (float)h[1]);
  h[2] = (_Float16)v.z; l[2] = (_Float16)(v.z - (float)h[2]);
  h[3] = (_Float16)v.w; l[3] = (_Float16)(v.w - (float)h[3]);
  *(f16x4*)(hi + (size_t)i * 4) = h;
  *(f16x4*)(lo + (size_t)i * 4) = l;
}

// ---- weights: W[12][K][128] + R[K][128] -> transposed fp16 [13][128][K] ----
__global__ __launch_bounds__(256) void wsplit(
    const float* __restrict__ W, const float* __restrict__ Rm,
    _Float16* __restrict__ th, int K)
{
  int idx = blockIdx.x * 256 + threadIdx.x;
  int total = 13 * 128 * K;
  if (idx >= total) return;
  int z = idx / (128 * K);
  int rem = idx - z * 128 * K;
  int n = rem / K;
  int k = rem - n * K;
  float v = (z < N_REL) ? W[((size_t)z * K + k) * 128 + n] : Rm[(size_t)k * 128 + n];
  th[idx] = (_Float16)v;
}

// ---------------- MFMA GEMM (glds + 2 barriers per K-step) ----------------
__global__ __launch_bounds__(256, 4) void gemm_mfma(
    const _Float16* __restrict__ Ah, const _Float16* __restrict__ Al,  // [M][K]
    const _Float16* __restrict__ Wh,   // [13][128][K]
    const float* __restrict__ bias,
    _Float16* __restrict__ Hc,         // [rc][M][128] fp16
    float* __restrict__ Cden,          // [M][128] fp32
    int M, int K, int r0, int rc, int zdim, int nwg)
{
  __shared__ _Float16 lds[3 * BMM * KSTEP];   // 24576 B
  _Float16* Ah_s = lds;
  _Float16* Al_s = lds + BMM * KSTEP;
  _Float16* B_s  = lds + 2 * BMM * KSTEP;

  int b = blockIdx.x;
  int q = nwg >> 3, rr = nwg & 7;
  int xcd = b & 7, ix = b >> 3;
  int wg = (xcd < rr ? xcd * (q + 1) : rr * (q + 1) + (xcd - rr) * q) + ix;
  int mt = wg / zdim;
  int z  = wg - mt * zdim;
  const bool is_root = (z >= rc);
  const int m0 = mt * BMM;

  const _Float16* __restrict__ b_src =
      Wh + (size_t)(is_root ? N_REL : (r0 + z)) * 128 * K;

  const int t = threadIdx.x;
  const int lane = t & 63;
  const int wave = t >> 6;
  const int wr = wave >> 1, wc = wave & 1;
  const int l16 = lane & 15, kq = lane >> 4;

  const int c0 = wave * 128 + lane;
  const int c1 = c0 + 64;
  const int cr0 = c0 >> 2, cs0 = (c0 & 3) << 3;
  const int cr1 = c1 >> 2, cs1 = (c1 & 3) << 3;
  int a0 = m0 + cr0; a0 = a0 < M ? a0 : M - 1;
  int a1 = m0 + cr1; a1 = a1 < M ? a1 : M - 1;
  const _Float16* gAh0 = Ah + (size_t)a0 * K + cs0;
  const _Float16* gAh1 = Ah + (size_t)a1 * K + cs1;
  const _Float16* gAl0 = Al + (size_t)a0 * K + cs0;
  const _Float16* gAl1 = Al + (size_t)a1 * K + cs1;
  const _Float16* gB0  = b_src + (size_t)cr0 * K + cs0;
  const _Float16* gB1  = b_src + (size_t)cr1 * K + cs1;
  _Float16* dAh = Ah_s + wave * 1024;
  _Float16* dAl = Al_s + wave * 1024;
  _Float16* dB  = B_s  + wave * 1024;

  f32x4v acc[4][4];
#pragma unroll
  for (int i = 0; i < 4; ++i)
#pragma unroll
    for (int j = 0; j < 4; ++j) acc[i][j] = (f32x4v){0.f, 0.f, 0.f, 0.f};

  for (int k0 = 0; k0 < K; k0 += KSTEP) {
    GLDS16(gAh0 + k0, dAh);
    GLDS16(gAh1 + k0, dAh + 512);
    GLDS16(gAl0 + k0, dAl);
    GLDS16(gAl1 + k0, dAl + 512);
    GLDS16(gB0  + k0, dB);
    GLDS16(gB1  + k0, dB + 512);
    __syncthreads();

    f16x8 fah[4], fal[4], fb[4];
#pragma unroll
    for (int i = 0; i < 4; ++i) {
      int ra = (wr * 64 + i * 16 + l16) * KSTEP + kq * 8;
      fah[i] = *(const f16x8*)&Ah_s[ra];
      fal[i] = *(const f16x8*)&Al_s[ra];
      int rb = (wc * 64 + i * 16 + l16) * KSTEP + kq * 8;
      fb[i]  = *(const f16x8*)&B_s[rb];
    }
#pragma unroll
    for (int i = 0; i < 4; ++i)
#pragma unroll
      for (int j = 0; j < 4; ++j) {
        acc[i][j] = __builtin_amdgcn_mfma_f32_16x16x32_f16(fah[i], fb[j], acc[i][j], 0, 0, 0);
        acc[i][j] = __builtin_amdgcn_mfma_f32_16x16x32_f16(fal[i], fb[j], acc[i][j], 0, 0, 0);
      }
    __syncthreads();
  }

  if (is_root) {
#pragma unroll
    for (int j = 0; j < 4; ++j) {
      int col = wc * 64 + j * 16 + l16;
      float bv = bias[col];
#pragma unroll
      for (int i = 0; i < 4; ++i)
#pragma unroll
        for (int rg = 0; rg < 4; ++rg) {
          int grow = m0 + wr * 64 + i * 16 + kq * 4 + rg;
          if (grow < M)
            __builtin_nontemporal_store(acc[i][j][rg] + bv,
                                        Cden + (size_t)grow * 128 + col);
        }
    }
  } else {
    _Float16* Cs = lds;
    _Float16* __restrict__ Crel = Hc + (size_t)z * M * 128;
#pragma unroll
    for (int h = 0; h < 2; ++h) {
      if (wr == h) {
#pragma unroll
        for (int i = 0; i < 4; ++i)
#pragma unroll
          for (int j = 0; j < 4; ++j)
#pragma unroll
            for (int rg = 0; rg < 4; ++rg)
              Cs[(i * 16 + kq * 4 + rg) * LDC + wc * 64 + j * 16 + l16] =
                  (_Float16)acc[i][j][rg];
      }
      __syncthreads();
#pragma unroll
      for (int p = 0; p < 4; ++p) {
        int q2 = t + 256 * p;
        int row = q2 >> 4, c16 = (q2 & 15) * 8;
        int gr = m0 + h * 64 + row;
        if (gr < M) {
          u32x4 v = *(const u32x4*)&Cs[row * LDC + c16];
          __builtin_nontemporal_store(v, (u32x4*)(Crel + (size_t)gr * 128 + c16));
        }
      }
      __syncthreads();
    }
  }
}

// ---------------- CSR build ----------------
__global__ void count_edges(const int* __restrict__ ei, const int* __restrict__ et,
                            int* __restrict__ deg, int* __restrict__ cnt) {
  int e = blockIdx.x * 256 + threadIdx.x;
  if (e >= N_EDGES) return;
  int d = ei[N_EDGES + e];
  int r = et[e];
  atomicAdd(&deg[d], 1);
  atomicAdd(&cnt[r * N_NODES + d], 1);
}

__global__ void inv_counts(const int* __restrict__ cnt, float* __restrict__ inv) {
  int i = blockIdx.x * 256 + threadIdx.x;
  if (i < N_REL * N_NODES) {
    int c = cnt[i];
    inv[i] = 1.0f / (float)(c > 1 ? c : 1);
  }
}

// ---- hierarchical scan: local scan -> scan block sums -> apply ----
__global__ __launch_bounds__(SCAN_B) void scan_local(
    const int* __restrict__ deg, int* __restrict__ locx, int* __restrict__ bsum) {
  __shared__ int buf[SCAN_B];
  int i = blockIdx.x * SCAN_B + threadIdx.x;
  int x = (i < N_NODES) ? deg[i] : 0;
  buf[threadIdx.x] = x;
  __syncthreads();
#pragma unroll
  for (int off = 1; off < SCAN_B; off <<= 1) {
    int t = (threadIdx.x >= off) ? buf[threadIdx.x - off] : 0;
    __syncthreads();
    buf[threadIdx.x] += t;
    __syncthreads();
  }
  if (i < N_NODES) locx[i] = buf[threadIdx.x] - x;   // exclusive
  if (threadIdx.x == SCAN_B - 1) bsum[blockIdx.x] = buf[threadIdx.x];
}

__global__ __launch_bounds__(64) void scan_bsums(int* __restrict__ bsum,
                                                 int* __restrict__ boff) {
  if (threadIdx.x == 0) {
    int run = 0;
    for (int j = 0; j < SCAN_NB; ++j) { boff[j] = run; run += bsum[j]; }
  }
}

__global__ __launch_bounds__(SCAN_B) void scan_apply(
    const int* __restrict__ locx, const int* __restrict__ boff,
    int* __restrict__ row_ptr, int* __restrict__ cursor) {
  int i = blockIdx.x * SCAN_B + threadIdx.x;
  if (i < N_NODES) {
    int rp = locx[i] + boff[blockIdx.x];
    row_ptr[i] = rp;
    cursor[i] = rp;
  }
  if (i == 0) row_ptr[N_NODES] = N_EDGES;
}

// pack per-edge {byte-offset into Hc, fp32 weight} as u64
__global__ void scatter_edges(const int* __restrict__ ei, const int* __restrict__ et,
                              const float* __restrict__ inv,
                              int* __restrict__ cursor,
                              unsigned long long* __restrict__ csr_ow) {
  int e = blockIdx.x * 256 + threadIdx.x;
  if (e >= N_EDGES) return;
  int s = ei[e];
  int d = ei[N_EDGES + e];
  int r = et[e];
  int pos = atomicAdd(&cursor[d], 1);
  unsigned off = ((unsigned)r * (unsigned)N_NODES + (unsigned)s) * 256u; // bytes
  float w = inv[r * N_NODES + d];
  union { float f; unsigned u; } wu; wu.f = w;
  csr_ow[pos] = (unsigned long long)off | ((unsigned long long)wu.u << 32);
}

__global__ void count_graphs(const int* __restrict__ batch, int* __restrict__ gcnt) {
  int i = blockIdx.x * 256 + threadIdx.x;
  if (i < N_NODES) atomicAdd(&gcnt[batch[i]], 1);
}

__device__ inline void fmacc(float2& acc, unsigned pv, float w) {
  union { unsigned u; _Float16 f[2]; } cv; cv.u = pv;
  acc.x += w * (float)cv.f[0];
  acc.y += w * (float)cv.f[1];
}

// ---- aggregation: wave/node, scalar (SGPR) descriptors, 4-deep gathers -----
__global__ __launch_bounds__(256) void aggregate(
    const _Float16* __restrict__ Hc,    // [rc][N][128] fp16 (full when rc==12)
    const int* __restrict__ row_ptr,
    const unsigned long long* __restrict__ csr_ow,
    float* __restrict__ h,              // [N][128] fp32, in/out
    _Float16* __restrict__ AhO, _Float16* __restrict__ AlO,
    int r0, int rc, int do_relu, int write_split, int write_f32)
{
  int v = blockIdx.x * 4 + (threadIdx.x >> 6);
  v = __builtin_amdgcn_readfirstlane(v);      // wave-uniform -> scalar loads
  if (v >= N_NODES) return;
  const int lane = threadIdx.x & 63;
  float2 acc = *(const float2*)&h[(size_t)v * 128 + lane * 2];
  const int e0 = row_ptr[v];
  const int e1 = row_ptr[v + 1];
  const char* __restrict__ HcB = (const char*)Hc;

  if (rc == N_REL) {
    int i = e0;
    for (; i + 4 <= e1; i += 4) {
      unsigned long long d0 = csr_ow[i + 0];   // scalar s_load (uniform addr)
      unsigned long long d1 = csr_ow[i + 1];
      unsigned long long d2 = csr_ow[i + 2];
      unsigned long long d3 = csr_ow[i + 3];
      unsigned p0 = *((const unsigned*)(HcB + (unsigned)d0) + lane);
      unsigned p1 = *((const unsigned*)(HcB + (unsigned)d1) + lane);
      unsigned p2 = *((const unsigned*)(HcB + (unsigned)d2) + lane);
      unsigned p3 = *((const unsigned*)(HcB + (unsigned)d3) + lane);
      fmacc(acc, p0, __uint_as_float((unsigned)(d0 >> 32)));
      fmacc(acc, p1, __uint_as_float((unsigned)(d1 >> 32)));
      fmacc(acc, p2, __uint_as_float((unsigned)(d2 >> 32)));
      fmacc(acc, p3, __uint_as_float((unsigned)(d3 >> 32)));
    }
    for (; i < e1; ++i) {
      unsigned long long d0 = csr_ow[i];
      unsigned p0 = *((const unsigned*)(HcB + (unsigned)d0) + lane);
      fmacc(acc, p0, __uint_as_float((unsigned)(d0 >> 32)));
    }
  } else {
    // chunked fallback (RC < 12): filter by relation range
    for (int i = e0; i < e1; ++i) {
      unsigned long long d0 = csr_ow[i];
      unsigned off = (unsigned)d0;
      unsigned rowi = off >> 8;
      unsigned r = rowi / (unsigned)N_NODES;
      if (r - (unsigned)r0 >= (unsigned)rc) continue;
      off -= (unsigned)r0 * (unsigned)N_NODES * 256u;
      unsigned p0 = *((const unsigned*)(HcB + off) + lane);
      fmacc(acc, p0, __uint_as_float((unsigned)(d0 >> 32)));
    }
  }

  if (do_relu) { acc.x = fmaxf(acc.x, 0.f); acc.y = fmaxf(acc.y, 0.f); }
  if (write_split) {
    union { _Float16 f[2]; unsigned u; } ph, pl;
    ph.f[0] = (_Float16)acc.x; ph.f[1] = (_Float16)acc.y;
    pl.f[0] = (_Float16)(acc.x - (float)ph.f[0]);
    pl.f[1] = (_Float16)(acc.y - (float)ph.f[1]);
    ((unsigned*)AhO)[(size_t)v * 64 + lane] = ph.u;
    ((unsigned*)AlO)[(size_t)v * 64 + lane] = pl.u;
  }
  if (write_f32) *(float2*)&h[(size_t)v * 128 + lane * 2] = acc;
}

// ---------------- final head/tail gather ----------------
__global__ __launch_bounds__(256) void final_gather(
    const float* __restrict__ h, const int* __restrict__ gcnt,
    const int* __restrict__ ih, const int* __restrict__ it,
    float* __restrict__ out)
{
  __shared__ int off_s;
  int g = blockIdx.x;
  if (threadIdx.x == 0) {
    int off = 0;
    for (int j = 0; j < g; ++j) off += gcnt[j];
    off_s = off;
  }
  __syncthreads();
  int off = off_s;
  int c = threadIdx.x;
  int hi = ih[g] + off;
  int ti = it[g] + off;
  out[(size_t)g * 256 + c] = (c < D_H) ? h[(size_t)hi * D_H + c]
                                       : h[(size_t)ti * D_H + (c - D_H)];
}

extern "C" void kernel_launch(void* const* d_in, const int* in_sizes, int n_in,
                              void* d_out, int out_size, void* d_ws, size_t ws_size,
                              hipStream_t stream) {
  (void)in_sizes; (void)n_in; (void)out_size;
  const float* x   = (const float*)d_in[0];
  const int* ei    = (const int*)d_in[1];
  const int* et    = (const int*)d_in[2];
  const int* batch = (const int*)d_in[3];
  const int* ih    = (const int*)d_in[4];
  const int* it    = (const int*)d_in[5];
  const float* Wl[5]; const float* Rl[5]; const float* Bl[5];
  for (int l = 0; l < 5; ++l) {
    Wl[l] = (const float*)d_in[6 + 3 * l];
    Rl[l] = (const float*)d_in[7 + 3 * l];
    Bl[l] = (const float*)d_in[8 + 3 * l];
  }

  char* p = (char*)d_ws;
  size_t used = 0;
  auto alloc = [&](size_t bytes) {
    char* r = p;
    size_t rb = (bytes + 255) & ~(size_t)255;
    p += rb; used += rb;
    return r;
  };
  const size_t HREL16 = (size_t)N_NODES * D_H * 2;
  float* h        = (float*)alloc((size_t)N_NODES * D_H * 4);
  _Float16* Ahb   = (_Float16*)alloc((size_t)N_NODES * D_IN * 2);
  _Float16* Alb   = (_Float16*)alloc((size_t)N_NODES * D_IN * 2);
  _Float16* Wh    = (_Float16*)alloc((size_t)13 * 128 * D_IN * 2);
  float* inv      = (float*)alloc((size_t)N_REL * N_NODES * 4);
  int* cnt        = (int*)alloc((size_t)N_REL * N_NODES * 4);
  int* deg        = (int*)alloc((size_t)N_NODES * 4);
  int* rowp       = (int*)alloc((size_t)(N_NODES + 1) * 4);
  int* cursor     = (int*)alloc((size_t)N_NODES * 4);
  int* locx       = (int*)alloc((size_t)N_NODES * 4);
  int* bsum       = (int*)alloc((size_t)SCAN_NB * 4);
  int* boff       = (int*)alloc((size_t)SCAN_NB * 4);
  unsigned long long* csr_ow = (unsigned long long*)alloc((size_t)N_EDGES * 8);
  int* gcnt       = (int*)alloc((size_t)N_GRAPH * 4);

  size_t remain = (ws_size > used) ? (ws_size - used) : 0;
  int RC = (int)(remain / HREL16);
  if (RC > N_REL) RC = N_REL;
  if (RC < 1) RC = 1;
  _Float16* Hc = (_Float16*)alloc((size_t)RC * HREL16);

  hipMemsetAsync(cnt, 0, (size_t)N_REL * N_NODES * 4, stream);
  hipMemsetAsync(deg, 0, (size_t)N_NODES * 4, stream);
  hipMemsetAsync(gcnt, 0, (size_t)N_GRAPH * 4, stream);

  count_edges<<<(N_EDGES + 255) / 256, 256, 0, stream>>>(ei, et, deg, cnt);
  inv_counts<<<(N_REL * N_NODES + 255) / 256, 256, 0, stream>>>(cnt, inv);
  scan_local<<<SCAN_NB, SCAN_B, 0, stream>>>(deg, locx, bsum);
  scan_bsums<<<1, 64, 0, stream>>>(bsum, boff);
  scan_apply<<<SCAN_NB, SCAN_B, 0, stream>>>(locx, boff, rowp, cursor);
  scatter_edges<<<(N_EDGES + 255) / 256, 256, 0, stream>>>(ei, et, inv, cursor, csr_ow);
  count_graphs<<<(N_NODES + 255) / 256, 256, 0, stream>>>(batch, gcnt);

  int n4 = N_NODES * D_IN / 4;
  split_f32<<<(n4 + 255) / 256, 256, 0, stream>>>(x, Ahb, Alb, n4);

  const int mtiles = (N_NODES + BMM - 1) / BMM;   // 391
  for (int l = 0; l < 5; ++l) {
    int K = (l == 0) ? D_IN : D_H;
    int wtot = 13 * 128 * K;
    wsplit<<<(wtot + 255) / 256, 256, 0, stream>>>(Wl[l], Rl[l], Wh, K);

    int nchunks = (N_REL + RC - 1) / RC;
    for (int ch = 0; ch < nchunks; ++ch) {
      int r0 = ch * RC;
      int rc = (N_REL - r0) < RC ? (N_REL - r0) : RC;
      int zdim = rc + (ch == 0 ? 1 : 0);
      int nwg = zdim * mtiles;
      gemm_mfma<<<nwg, 256, 0, stream>>>(Ahb, Alb, Wh, Bl[l], Hc, h,
                                         N_NODES, K, r0, rc, zdim, nwg);
      int final_ch = (ch == nchunks - 1);
      int relu  = (l < 4 && final_ch) ? 1 : 0;
      int wspl  = (l < 4 && final_ch) ? 1 : 0;
      int wf32  = (!final_ch || l == 4) ? 1 : 0;
      aggregate<<<(N_NODES + 3) / 4, 256, 0, stream>>>(Hc, rowp, csr_ow,
                                                       h, Ahb, Alb,
                                                       r0, rc, relu, wspl, wf32);
    }
  }

  final_gather<<<N_GRAPH, 256, 0, stream>>>(h, gcnt, ih, it, (float*)d_out);
}